// Round 16
// baseline (436.302 us; speedup 1.0000x reference)
//
#include <hip/hip_runtime.h>

#define NN 41472
#define NE 829440

typedef __attribute__((ext_vector_type(8))) short short8;
typedef __attribute__((ext_vector_type(4))) float f32x4;
typedef __attribute__((ext_vector_type(16))) float f32x16;
typedef __attribute__((ext_vector_type(4))) float float4v;
typedef __attribute__((ext_vector_type(4))) unsigned u32x4;

// ---- ws layout (bytes) ----
#define FLG_OFF   0
#define AGG_OFF   256
#define AGG_BYTES 15925248               // NN*96*4
#define W1F_OFF   (AGG_OFF + AGG_BYTES)  // msg W1 32x32 frags: 13*3*1024 = 39936
#define W2F_OFF   (W1F_OFF + 39936)
#define W3F_OFF   (W2F_OFF + 18432)
#define P1F_OFF   (W3F_OFF + 18432)
#define P2F_OFF   (P1F_OFF + 24576)
#define P3F_OFF   (P2F_OFF + 18432)
#define IHF_OFF   (P3F_OFF + 18432)
#define HHF_OFF   (IHF_OFF + 73728)
#define NB16_OFF  (HHF_OFF + 73728)      // nodes bf16: NN*96*2 = 7962624
#define CUR_OFF   (NB16_OFF + 7962624)   // counts/cursors: NN*4 = 165888
#define BSUM_OFF  (CUR_OFF + 165888)     // 41 block sums
#define SRT_OFF   (BSUM_OFF + 256)       // sorted (src,dst): NE*8 = 6635520
#define SID_OFF   (SRT_OFF + 6635520)    // (unused slot) NE*4
#define EFB_OFF   (SID_OFF + 3317760)    // sorted ef bf16: NE*16*2 = 26542080
#define WS_NEED   (EFB_OFF + 26542080)   // ~60.9 MB (proven available)

static __device__ __forceinline__ float bf2f(short s) {
  unsigned u = ((unsigned)(unsigned short)s) << 16;
  return __builtin_bit_cast(float, u);
}
static __device__ __forceinline__ short f2bf(float f) {
  unsigned u = __builtin_bit_cast(unsigned, f);
  unsigned r = (u + 0x7fffu + ((u >> 16) & 1u)) >> 16;
  return (short)r;
}
static __device__ __forceinline__ unsigned cvtpk(float lo, float hi) {
  unsigned r;
  asm("v_cvt_pk_bf16_f32 %0, %1, %2" : "=v"(r) : "v"(lo), "v"(hi));
  return r;
}
static __device__ __forceinline__ f32x4 fzero() { f32x4 z = {0.f, 0.f, 0.f, 0.f}; return z; }
static __device__ __forceinline__ f32x16 f16zero() {
  f32x16 z;
#pragma unroll
  for (int i = 0; i < 16; ++i) z[i] = 0.f;
  return z;
}
static __device__ __forceinline__ short8 szero() { short8 z = {0,0,0,0,0,0,0,0}; return z; }
static __device__ __forceinline__ float sigm(float x) { return 1.f / (1.f + __expf(-x)); }
static __device__ __forceinline__ float tanh_f(float x) {
  float ax = fabsf(x);
  float e  = __expf(-2.f * ax);
  float t  = (1.f - e) / (1.f + e);
  return copysignf(t, x);
}
static __device__ __forceinline__ int clampn(int v) {
  unsigned u = (unsigned)v;
  return (u < (unsigned)NN) ? v : 0;
}
static __device__ __forceinline__ float ldf(const void* base, size_t i, int f32) {
  return f32 ? ((const float*)base)[i] : bf2f(((const short*)base)[i]);
}
static __device__ __forceinline__ short8 ld8(const void* base, size_t i, int f32) {
  if (f32) {
    const float* p = (const float*)base + i;
    float4v a = *(const float4v*)p;
    float4v b = *(const float4v*)(p + 4);
    u32x4 u;
    u[0] = cvtpk(a[0], a[1]); u[1] = cvtpk(a[2], a[3]);
    u[2] = cvtpk(b[0], b[1]); u[3] = cvtpk(b[2], b[3]);
    return __builtin_bit_cast(short8, u);
  }
  return *(const short8*)((const short*)base + i);
}
static __device__ __forceinline__ short8 ldrow8(const void* base, size_t i, int f32) {
  if (f32) {
    const float* p = (const float*)base + i;
    short8 r;
#pragma unroll
    for (int j = 0; j < 8; ++j) r[j] = f2bf(p[j]);
    return r;
  }
  return *(const short8*)((const short*)base + i);
}
static __device__ __forceinline__ int ldedge(const int* e, int flat, int e64) {
  return e64 ? e[2 * flat] : e[flat];
}

// ---------------- dtype sniffing (wave-parallel) ----------------
__global__ __launch_bounds__(64) void sniff_kernel(const unsigned* __restrict__ nodes_u,
                                                   const int* __restrict__ edges_i,
                                                   int* __restrict__ flags) {
  int l = threadIdx.x;
  int votes = 0;
  for (int i = l; i < 256; i += 64) {
    unsigned u = nodes_u[i];
    int ex = (int)((u >> 23) & 0xFFu);
    if (ex >= 116 && ex <= 134) votes++;
  }
  int z = 0;
  for (int i = l; i < 128; i += 64) if (edges_i[2 * i + 1] == 0) z++;
#pragma unroll
  for (int o = 32; o; o >>= 1) { votes += __shfl_down(votes, o); z += __shfl_down(z, o); }
  if (l == 0) {
    flags[0] = (votes >= 160) ? 1 : 0;   // 1 => float arrays are fp32
    flags[1] = (z == 128) ? 1 : 0;       // 1 => edges are int64
  }
}

// zero agg (995328 float4s) + cur (NN ints), grid 3888x256
__global__ __launch_bounds__(256) void zero_all_kernel(float4v* __restrict__ agg4,
                                                       int* __restrict__ cur) {
  int i = blockIdx.x * 256 + threadIdx.x;
  agg4[i] = float4v{0.f, 0.f, 0.f, 0.f};
  if (i < NN) cur[i] = 0;
}

// ---------------- fused: edge histogram + nodes->bf16 copy (grid 3240x256) ----------------
__global__ __launch_bounds__(256) void nb16hist_kernel(const void* __restrict__ nodes,
                                                       const char* __restrict__ ws,
                                                       short8* __restrict__ out,
                                                       const int* __restrict__ edges,
                                                       int* __restrict__ cnt) {
  const int f32 = ((const int*)(ws + FLG_OFF))[0];
  const int e64 = ((const int*)(ws + FLG_OFF))[1];
  int gid = blockIdx.x * 256 + threadIdx.x;
  int s = clampn(ldedge(edges, 2 * gid, e64));
  atomicAdd(&cnt[s], 1);
  if (gid < NN * 96 / 8) out[gid] = ld8(nodes, (size_t)gid * 8, f32);
}

__global__ __launch_bounds__(1024) void scan_local_kernel(int* __restrict__ cnt,
                                                          int* __restrict__ bsum) {
  __shared__ int tmp[1024];
  const int t = threadIdx.x;
  const int i = blockIdx.x * 1024 + t;
  int v = (i < NN) ? cnt[i] : 0;
  tmp[t] = v;
  __syncthreads();
  for (int ofs = 1; ofs < 1024; ofs <<= 1) {
    int x = (t >= ofs) ? tmp[t - ofs] : 0;
    __syncthreads();
    tmp[t] += x;
    __syncthreads();
  }
  if (i < NN) cnt[i] = tmp[t] - v;   // block-local exclusive
  if (t == 1023) bsum[blockIdx.x] = tmp[1023];
}

// single-wave exclusive scan over <=64 block sums
__global__ __launch_bounds__(64) void scan_tops_kernel(int* __restrict__ bsum, int nb) {
  int l = threadIdx.x;
  int v = (l < nb) ? bsum[l] : 0;
  int x = v;
#pragma unroll
  for (int o = 1; o < 64; o <<= 1) {
    int y = __shfl_up(x, o);
    if (l >= o) x += y;
  }
  if (l < nb) bsum[l] = x - v;
}

__global__ __launch_bounds__(1024) void scan_add_kernel(int* __restrict__ cnt,
                                                        const int* __restrict__ bsum) {
  int i = blockIdx.x * 1024 + threadIdx.x;
  if (i < NN) cnt[i] += bsum[blockIdx.x];
}

// scatter + pre-permute ef into sorted order as bf16
__global__ __launch_bounds__(256) void scatter_kernel(const int* __restrict__ edges,
                                                      const void* __restrict__ ef,
                                                      const char* __restrict__ ws,
                                                      int* __restrict__ cur,
                                                      int2* __restrict__ sdst,
                                                      short* __restrict__ efb) {
  const int f32 = ((const int*)(ws + FLG_OFF))[0];
  const int e64 = ((const int*)(ws + FLG_OFF))[1];
  int e = blockIdx.x * 256 + threadIdx.x;
  int s = clampn(ldedge(edges, 2 * e, e64));
  int d = clampn(ldedge(edges, 2 * e + 1, e64));
  int pos = atomicAdd(&cur[s], 1);
  sdst[pos] = make_int2(s, d);
  short8 lo = ld8(ef, (size_t)e * 16, f32);
  short8 hi = ld8(ef, (size_t)e * 16 + 8, f32);
  *(short8*)(efb + (size_t)pos * 16) = lo;
  *(short8*)(efb + (size_t)pos * 16 + 8) = hi;
}

// ---------------- weight relayout (natural layouts) ----------------
// fmt32 (32x32x16): elem j of lane l = W[ks*16+(l>>5)*8+j][nt*32+(l&31)]
// fmt16 (16x16x32): elem j of lane l = W[ks*32+(l>>4)*8+j][nt*16+(l&15)]
__global__ __launch_bounds__(64) void relayout_kernel(
    const void* __restrict__ mW1, const void* __restrict__ mW2, const void* __restrict__ mW3,
    const void* __restrict__ pW1, const void* __restrict__ pW2, const void* __restrict__ pW3,
    const void* __restrict__ Wih, const void* __restrict__ Whh, char* __restrict__ ws)
{
  const int f32 = ((const int*)(ws + FLG_OFF))[0];
  int c = blockIdx.x;
  int l = threadIdx.x;
  const void* W; int K, NOUT, NT, fmt32; size_t off;
  if (c < 39)       {          W = mW1; K = 208; NOUT = 96;  NT = 3;  off = W1F_OFF; fmt32 = 1; }
  else if (c < 57)  { c -= 39;  W = mW2; K = 96;  NOUT = 96;  NT = 3;  off = W2F_OFF; fmt32 = 1; }
  else if (c < 75)  { c -= 57;  W = mW3; K = 96;  NOUT = 96;  NT = 3;  off = W3F_OFF; fmt32 = 1; }
  else if (c < 99)  { c -= 75;  W = pW1; K = 112; NOUT = 96;  NT = 6;  off = P1F_OFF; fmt32 = 0; }
  else if (c < 117) { c -= 99;  W = pW2; K = 96;  NOUT = 96;  NT = 6;  off = P2F_OFF; fmt32 = 0; }
  else if (c < 135) { c -= 117; W = pW3; K = 96;  NOUT = 96;  NT = 6;  off = P3F_OFF; fmt32 = 0; }
  else if (c < 207) { c -= 135; W = Wih; K = 96;  NOUT = 384; NT = 24; off = IHF_OFF; fmt32 = 0; }
  else              { c -= 207; W = Whh; K = 96;  NOUT = 384; NT = 24; off = HHF_OFF; fmt32 = 0; }
  int ks = c / NT, nt = c % NT;
  short8 v;
#pragma unroll
  for (int j = 0; j < 8; ++j) {
    int k, n;
    if (fmt32) { k = ks * 16 + (l >> 5) * 8 + j; n = nt * 32 + (l & 31); }
    else       { k = ks * 32 + (l >> 4) * 8 + j; n = nt * 16 + (l & 15); }
    v[j] = (k < K) ? f2bf(ldf(W, (size_t)k * NOUT + n, f32)) : (short)0;
  }
  short8* dst = (short8*)(ws + off);
  dst[c * 64 + l] = v;
}

// ---------------- edge message MLP (r7-proven: w2+w3 LDS-staged) ----------------
// 256 threads = 4 waves, 32 edges/wave, contiguous chunks of 128-edge batches.
// LDS: w2f (18KB) + w3f (18KB) + act (26.6KB) = 62KB -> 2 blocks/CU.
template<int SORTED>
__global__ __launch_bounds__(256, 2) void edge_kernel(
    const void* __restrict__ nodes, const void* __restrict__ ef,
    const int* __restrict__ edges,
    const void* __restrict__ b1, const void* __restrict__ b2, const void* __restrict__ b3,
    const char* __restrict__ ws, float* __restrict__ agg)
{
  __shared__ __align__(16) short w2f[9216];
  __shared__ __align__(16) short w3f[9216];
  __shared__ __align__(16) short act[4][3328];

  const int f32 = ((const int*)(ws + FLG_OFF))[0];
  const int e64 = ((const int*)(ws + FLG_OFF))[1];
  const short* nb16 = (const short*)(ws + NB16_OFF);
  const int2*  sdst = (const int2*)(ws + SRT_OFF);
  const short* efb  = (const short*)(ws + EFB_OFF);

  {
    const short8* s2 = (const short8*)(ws + W2F_OFF);
    const short8* s3 = (const short8*)(ws + W3F_OFF);
    short8* d2 = (short8*)w2f;
    short8* d3 = (short8*)w3f;
    for (int i = threadIdx.x; i < 1152; i += 256) d2[i] = s2[i];
    for (int i = threadIdx.x; i < 1152; i += 256) d3[i] = s3[i];
  }
  __syncthreads();

  const int wv  = threadIdx.x >> 6;
  const int l   = threadIdx.x & 63;
  const int e31 = l & 31;
  const int hi  = l >> 5;
  short* aw = act[wv];
  const short8* w1g = (const short8*)(ws + W1F_OFF);

  const float B1[3] = {ldf(b1, e31, f32), ldf(b1, 32 + e31, f32), ldf(b1, 64 + e31, f32)};
  const float B2[3] = {ldf(b2, e31, f32), ldf(b2, 32 + e31, f32), ldf(b2, 64 + e31, f32)};
  const float B3[3] = {ldf(b3, e31, f32), ldf(b3, 32 + e31, f32), ldf(b3, 64 + e31, f32)};

  const int nbat = NE / 128;
  const int chunk = (nbat + gridDim.x - 1) / gridDim.x;
  const int it0 = blockIdx.x * chunk;
  int it1 = it0 + chunk; if (it1 > nbat) it1 = nbat;

  for (int it = it0; it < it1; ++it) {
    const int base = it * 128 + wv * 32;
    const int eL = base + e31;
    int src, dst;
    if (SORTED) {
      int2 sd = sdst[eL];
      src = clampn(sd.x); dst = clampn(sd.y);
    } else {
      src = clampn(ldedge(edges, 2 * eL, e64));
      dst = clampn(ldedge(edges, 2 * eL + 1, e64));
    }

    f32x16 a0 = f16zero(), a1 = f16zero(), a2 = f16zero();

    // ---- L1: K = 208 = 6ks src | 6ks dst | 1ks ef ----
#pragma unroll
    for (int ks = 0; ks < 6; ++ks) {
      short8 a = SORTED ? *(const short8*)(nb16 + (size_t)src * 96 + ks * 16 + hi * 8)
                        : ld8(nodes, (size_t)src * 96 + ks * 16 + hi * 8, f32);
      a0 = __builtin_amdgcn_mfma_f32_32x32x16_bf16(a, w1g[(ks * 3 + 0) * 64 + l], a0, 0, 0, 0);
      a1 = __builtin_amdgcn_mfma_f32_32x32x16_bf16(a, w1g[(ks * 3 + 1) * 64 + l], a1, 0, 0, 0);
      a2 = __builtin_amdgcn_mfma_f32_32x32x16_bf16(a, w1g[(ks * 3 + 2) * 64 + l], a2, 0, 0, 0);
    }
#pragma unroll
    for (int ks = 6; ks < 12; ++ks) {
      short8 a = SORTED ? *(const short8*)(nb16 + (size_t)dst * 96 + (ks - 6) * 16 + hi * 8)
                        : ld8(nodes, (size_t)dst * 96 + (ks - 6) * 16 + hi * 8, f32);
      a0 = __builtin_amdgcn_mfma_f32_32x32x16_bf16(a, w1g[(ks * 3 + 0) * 64 + l], a0, 0, 0, 0);
      a1 = __builtin_amdgcn_mfma_f32_32x32x16_bf16(a, w1g[(ks * 3 + 1) * 64 + l], a1, 0, 0, 0);
      a2 = __builtin_amdgcn_mfma_f32_32x32x16_bf16(a, w1g[(ks * 3 + 2) * 64 + l], a2, 0, 0, 0);
    }
    {
      short8 a = SORTED ? *(const short8*)(efb + (size_t)eL * 16 + hi * 8)
                        : ld8(ef, (size_t)eL * 16 + hi * 8, f32);
      a0 = __builtin_amdgcn_mfma_f32_32x32x16_bf16(a, w1g[(12 * 3 + 0) * 64 + l], a0, 0, 0, 0);
      a1 = __builtin_amdgcn_mfma_f32_32x32x16_bf16(a, w1g[(12 * 3 + 1) * 64 + l], a1, 0, 0, 0);
      a2 = __builtin_amdgcn_mfma_f32_32x32x16_bf16(a, w1g[(12 * 3 + 2) * 64 + l], a2, 0, 0, 0);
    }
#pragma unroll
    for (int r = 0; r < 16; ++r) {
      int row = (r & 3) + 8 * (r >> 2) + 4 * hi;
      aw[row * 104 +  0 + e31] = f2bf(fmaxf(a0[r] + B1[0], 0.f));
      aw[row * 104 + 32 + e31] = f2bf(fmaxf(a1[r] + B1[1], 0.f));
      aw[row * 104 + 64 + e31] = f2bf(fmaxf(a2[r] + B1[2], 0.f));
    }
    asm volatile("s_waitcnt lgkmcnt(0)" ::: "memory");
    __builtin_amdgcn_sched_barrier(0);

    // ---- L2 (weights from LDS) ----
    f32x16 c0 = f16zero(), c1 = f16zero(), c2 = f16zero();
#pragma unroll
    for (int ks = 0; ks < 6; ++ks) {
      short8 a = *(const short8*)&aw[e31 * 104 + ks * 16 + hi * 8];
      c0 = __builtin_amdgcn_mfma_f32_32x32x16_bf16(a, *(const short8*)&w2f[((ks * 3 + 0) * 64 + l) * 8], c0, 0, 0, 0);
      c1 = __builtin_amdgcn_mfma_f32_32x32x16_bf16(a, *(const short8*)&w2f[((ks * 3 + 1) * 64 + l) * 8], c1, 0, 0, 0);
      c2 = __builtin_amdgcn_mfma_f32_32x32x16_bf16(a, *(const short8*)&w2f[((ks * 3 + 2) * 64 + l) * 8], c2, 0, 0, 0);
    }
#pragma unroll
    for (int r = 0; r < 16; ++r) {
      int row = (r & 3) + 8 * (r >> 2) + 4 * hi;
      aw[row * 104 +  0 + e31] = f2bf(fmaxf(c0[r] + B2[0], 0.f));
      aw[row * 104 + 32 + e31] = f2bf(fmaxf(c1[r] + B2[1], 0.f));
      aw[row * 104 + 64 + e31] = f2bf(fmaxf(c2[r] + B2[2], 0.f));
    }
    asm volatile("s_waitcnt lgkmcnt(0)" ::: "memory");
    __builtin_amdgcn_sched_barrier(0);

    // ---- L3 (weights from LDS) ----
    f32x16 d0 = f16zero(), d1 = f16zero(), d2 = f16zero();
#pragma unroll
    for (int ks = 0; ks < 6; ++ks) {
      short8 a = *(const short8*)&aw[e31 * 104 + ks * 16 + hi * 8];
      d0 = __builtin_amdgcn_mfma_f32_32x32x16_bf16(a, *(const short8*)&w3f[((ks * 3 + 0) * 64 + l) * 8], d0, 0, 0, 0);
      d1 = __builtin_amdgcn_mfma_f32_32x32x16_bf16(a, *(const short8*)&w3f[((ks * 3 + 1) * 64 + l) * 8], d1, 0, 0, 0);
      d2 = __builtin_amdgcn_mfma_f32_32x32x16_bf16(a, *(const short8*)&w3f[((ks * 3 + 2) * 64 + l) * 8], d2, 0, 0, 0);
    }
    asm volatile("s_waitcnt lgkmcnt(0)" ::: "memory");
    __builtin_amdgcn_sched_barrier(0);

    // ---- segment-sum by src ----
    if (SORTED) {
      int se[16];
#pragma unroll
      for (int r = 0; r < 16; ++r) {
        int row = (r & 3) + 8 * (r >> 2) + 4 * hi;
        se[r] = __shfl(src, row, 64);
      }
      float s0 = d0[0], s1 = d1[0], s2 = d2[0];
      int cu = se[0], cnt = 1;
#pragma unroll
      for (int r = 1; r < 16; ++r) {
        if (se[r] == cu) {
          s0 += d0[r]; s1 += d1[r]; s2 += d2[r]; cnt++;
        } else {
          atomicAdd(&agg[(size_t)cu * 96 +      e31], s0 + cnt * B3[0]);
          atomicAdd(&agg[(size_t)cu * 96 + 32 + e31], s1 + cnt * B3[1]);
          atomicAdd(&agg[(size_t)cu * 96 + 64 + e31], s2 + cnt * B3[2]);
          cu = se[r]; s0 = d0[r]; s1 = d1[r]; s2 = d2[r]; cnt = 1;
        }
      }
      atomicAdd(&agg[(size_t)cu * 96 +      e31], s0 + cnt * B3[0]);
      atomicAdd(&agg[(size_t)cu * 96 + 32 + e31], s1 + cnt * B3[1]);
      atomicAdd(&agg[(size_t)cu * 96 + 64 + e31], s2 + cnt * B3[2]);
    } else {
#pragma unroll
      for (int r = 0; r < 16; ++r) {
        int row = (r & 3) + 8 * (r >> 2) + 4 * hi;
        int s = clampn(ldedge(edges, 2 * (base + row), e64));
        atomicAdd(&agg[(size_t)s * 96 +      e31], d0[r] + B3[0]);
        atomicAdd(&agg[(size_t)s * 96 + 32 + e31], d1[r] + B3[1]);
        atomicAdd(&agg[(size_t)s * 96 + 64 + e31], d2[r] + B3[2]);
      }
    }
  }
}

// ---------------- node: post-MLP + LSTM + fused output head ----------------
__global__ __launch_bounds__(512, 1) void node_kernel(
    const float* __restrict__ agg, const void* __restrict__ puzzle,
    const void* __restrict__ h, const void* __restrict__ c,
    const void* __restrict__ pb1, const void* __restrict__ pb2, const void* __restrict__ pb3,
    const void* __restrict__ bih, const void* __restrict__ bhh,
    const void* __restrict__ oW, const void* __restrict__ ob,
    const char* __restrict__ ws,
    float* __restrict__ oh0, float* __restrict__ oh1, float* __restrict__ oc,
    float* __restrict__ oo)
{
  __shared__ __align__(16) short p2f[9216];
  __shared__ __align__(16) short p3f[9216];
  __shared__ __align__(16) short act[8][16][104];

  const int f32 = ((const int*)(ws + FLG_OFF))[0];

  {
    const short8* s2 = (const short8*)(ws + P2F_OFF);
    const short8* s3 = (const short8*)(ws + P3F_OFF);
    short8* d2 = (short8*)p2f;
    short8* d3 = (short8*)p3f;
    for (int i = threadIdx.x; i < 1152; i += 512) d2[i] = s2[i];
    for (int i = threadIdx.x; i < 1152; i += 512) d3[i] = s3[i];
  }
  __syncthreads();

  const int wv = threadIdx.x >> 6;
  const int l  = threadIdx.x & 63;
  const int lg = l >> 4, lr = l & 15;
  const int n0 = blockIdx.x * 128 + wv * 16;
  const int row = n0 + lr;

  const short8* p1g = (const short8*)(ws + P1F_OFF);
  const short8* ihg = (const short8*)(ws + IHF_OFF);
  const short8* hhg = (const short8*)(ws + HHF_OFF);

  f32x4 acc[6];
#pragma unroll
  for (int nt = 0; nt < 6; ++nt) acc[nt] = fzero();

#pragma unroll
  for (int ks = 0; ks < 3; ++ks) {
    const float* p = agg + (size_t)row * 96 + ks * 32 + lg * 8;
    short8 ahi, alo;
#pragma unroll
    for (int j = 0; j < 8; ++j) {
      float v = p[j];
      short hiq = f2bf(v);
      ahi[j] = hiq;
      alo[j] = f2bf(v - bf2f(hiq));
    }
#pragma unroll
    for (int nt = 0; nt < 6; ++nt) {
      short8 b = p1g[(ks * 6 + nt) * 64 + l];
      acc[nt] = __builtin_amdgcn_mfma_f32_16x16x32_bf16(ahi, b, acc[nt], 0, 0, 0);
      acc[nt] = __builtin_amdgcn_mfma_f32_16x16x32_bf16(alo, b, acc[nt], 0, 0, 0);
    }
  }
  {
    short8 a;
    if (lg < 2) a = ldrow8(puzzle, (size_t)row * 16 + lg * 8, f32);
    else        a = szero();
#pragma unroll
    for (int nt = 0; nt < 6; ++nt) {
      short8 b = p1g[(3 * 6 + nt) * 64 + l];
      acc[nt] = __builtin_amdgcn_mfma_f32_16x16x32_bf16(a, b, acc[nt], 0, 0, 0);
    }
  }
#pragma unroll
  for (int nt = 0; nt < 6; ++nt) {
    float bb = ldf(pb1, nt * 16 + lr, f32);
#pragma unroll
    for (int r = 0; r < 4; ++r) {
      float v = fmaxf(acc[nt][r] + bb, 0.f);
      act[wv][lg * 4 + r][nt * 16 + lr] = f2bf(v);
    }
    acc[nt] = fzero();
  }
  __syncthreads();

#pragma unroll
  for (int ks = 0; ks < 3; ++ks) {
    short8 a = *(const short8*)&act[wv][lr][ks * 32 + lg * 8];
#pragma unroll
    for (int nt = 0; nt < 6; ++nt) {
      short8 b = *(const short8*)&p2f[((ks * 6 + nt) * 64 + l) * 8];
      acc[nt] = __builtin_amdgcn_mfma_f32_16x16x32_bf16(a, b, acc[nt], 0, 0, 0);
    }
  }
  __syncthreads();
#pragma unroll
  for (int nt = 0; nt < 6; ++nt) {
    float bb = ldf(pb2, nt * 16 + lr, f32);
#pragma unroll
    for (int r = 0; r < 4; ++r) {
      float v = fmaxf(acc[nt][r] + bb, 0.f);
      act[wv][lg * 4 + r][nt * 16 + lr] = f2bf(v);
    }
    acc[nt] = fzero();
  }
  __syncthreads();

#pragma unroll
  for (int ks = 0; ks < 3; ++ks) {
    short8 a = *(const short8*)&act[wv][lr][ks * 32 + lg * 8];
#pragma unroll
    for (int nt = 0; nt < 6; ++nt) {
      short8 b = *(const short8*)&p3f[((ks * 6 + nt) * 64 + l) * 8];
      acc[nt] = __builtin_amdgcn_mfma_f32_16x16x32_bf16(a, b, acc[nt], 0, 0, 0);
    }
  }
  __syncthreads();
#pragma unroll
  for (int nt = 0; nt < 6; ++nt) {
    float bb = ldf(pb3, nt * 16 + lr, f32);
#pragma unroll
    for (int r = 0; r < 4; ++r) {
      act[wv][lg * 4 + r][nt * 16 + lr] = f2bf(acc[nt][r] + bb);
    }
  }
  __syncthreads();

  f32x4 g[24];
#pragma unroll
  for (int nt = 0; nt < 24; ++nt) g[nt] = fzero();
#pragma unroll
  for (int ks = 0; ks < 3; ++ks) {
    short8 ax = *(const short8*)&act[wv][lr][ks * 32 + lg * 8];
    short8 ah = ldrow8(h, (size_t)row * 96 + ks * 32 + lg * 8, f32);
#pragma unroll
    for (int nt = 0; nt < 24; ++nt) {
      short8 bi = ihg[(ks * 24 + nt) * 64 + l];
      g[nt] = __builtin_amdgcn_mfma_f32_16x16x32_bf16(ax, bi, g[nt], 0, 0, 0);
      short8 bh = hhg[(ks * 24 + nt) * 64 + l];
      g[nt] = __builtin_amdgcn_mfma_f32_16x16x32_bf16(ah, bh, g[nt], 0, 0, 0);
    }
  }

  // LSTM elementwise + fp32 writeback; h_new also stashed (bf16) into act for the head
#pragma unroll
  for (int nt = 0; nt < 6; ++nt) {
    int col = nt * 16 + lr;
    float bi_i = ldf(bih, col, f32)       + ldf(bhh, col, f32);
    float bi_f = ldf(bih, 96 + col, f32)  + ldf(bhh, 96 + col, f32);
    float bi_g = ldf(bih, 192 + col, f32) + ldf(bhh, 192 + col, f32);
    float bi_o = ldf(bih, 288 + col, f32) + ldf(bhh, 288 + col, f32);
#pragma unroll
    for (int r = 0; r < 4; ++r) {
      int node = n0 + lg * 4 + r;
      float iv = g[nt][r]      + bi_i;
      float fv = g[nt + 6][r]  + bi_f;
      float gv = g[nt + 12][r] + bi_g;
      float ov = g[nt + 18][r] + bi_o;
      float cv = ldf(c, (size_t)node * 96 + col, f32);
      float cn = sigm(fv) * cv + sigm(iv) * tanh_f(gv);
      float hn = sigm(ov) * tanh_f(cn);
      oh0[(size_t)node * 96 + col] = hn;
      oh1[(size_t)node * 96 + col] = hn;
      oc [(size_t)node * 96 + col] = cn;
      act[wv][lg * 4 + r][col] = f2bf(hn);
    }
  }
  __syncthreads();

  // ---- fused head: out[node][o] = ob[o] + h_new . oW[:,o] (128 nodes x 10 outs) ----
  const int nb0 = blockIdx.x * 128;
  for (int idx = threadIdx.x; idx < 1280; idx += 512) {
    int node16 = idx / 10;     // 0..127
    int o = idx - node16 * 10;
    const short* hrow = &act[node16 >> 4][node16 & 15][0];
    float a2 = ldf(ob, o, f32);
    for (int k = 0; k < 96; ++k)
      a2 = fmaf(bf2f(hrow[k]), ldf(oW, (size_t)k * 10 + o, f32), a2);
    oo[(size_t)(nb0 + node16) * 10 + o] = a2;
  }
}

extern "C" void kernel_launch(void* const* d_in, const int* in_sizes, int n_in,
                              void* d_out, int out_size, void* d_ws, size_t ws_size,
                              hipStream_t stream)
{
  const void* puzzle = d_in[0];
  const void* nodes  = d_in[1];
  const void* ef     = d_in[2];
  const void* h      = d_in[3];
  const void* c      = d_in[4];
  const int*  edges  = (const int*)d_in[5];
  const void* mW1 = d_in[6];  const void* mb1 = d_in[7];
  const void* mW2 = d_in[8];  const void* mb2 = d_in[9];
  const void* mW3 = d_in[10]; const void* mb3 = d_in[11];
  const void* pW1 = d_in[12]; const void* pb1 = d_in[13];
  const void* pW2 = d_in[14]; const void* pb2 = d_in[15];
  const void* pW3 = d_in[16]; const void* pb3 = d_in[17];
  const void* Wih = d_in[18]; const void* bih = d_in[19];
  const void* Whh = d_in[20]; const void* bhh = d_in[21];
  const void* oW  = d_in[22]; const void* ob  = d_in[23];

  char*  ws  = (char*)d_ws;
  int* flags = (int*)(ws + FLG_OFF);
  float* agg = (float*)(ws + AGG_OFF);
  int* cur = (int*)(ws + CUR_OFF);
  float* out = (float*)d_out;
  float* oh0 = out;
  float* oh1 = out + (size_t)NN * 96;
  float* oc  = out + (size_t)2 * NN * 96;
  float* oo  = out + (size_t)3 * NN * 96;

  sniff_kernel<<<1, 64, 0, stream>>>((const unsigned*)nodes, edges, flags);
  zero_all_kernel<<<3888, 256, 0, stream>>>((float4v*)agg, cur);
  relayout_kernel<<<279, 64, 0, stream>>>(mW1, mW2, mW3, pW1, pW2, pW3, Wih, Whh, ws);

  if (ws_size >= (size_t)WS_NEED) {
    int* bsum = (int*)(ws + BSUM_OFF);
    int2* sdst = (int2*)(ws + SRT_OFF);
    short* efb = (short*)(ws + EFB_OFF);
    const int nb = (NN + 1023) / 1024;   // 41

    nb16hist_kernel<<<NE / 256, 256, 0, stream>>>(nodes, ws, (short8*)(ws + NB16_OFF),
                                                  edges, cur);
    scan_local_kernel<<<nb, 1024, 0, stream>>>(cur, bsum);
    scan_tops_kernel<<<1, 64, 0, stream>>>(bsum, nb);
    scan_add_kernel<<<nb, 1024, 0, stream>>>(cur, bsum);
    scatter_kernel<<<NE / 256, 256, 0, stream>>>(edges, ef, ws, cur, sdst, efb);
    edge_kernel<1><<<512, 256, 0, stream>>>(nodes, ef, edges, mb1, mb2, mb3, ws, agg);
  } else {
    edge_kernel<0><<<512, 256, 0, stream>>>(nodes, ef, edges, mb1, mb2, mb3, ws, agg);
  }

  node_kernel<<<NN / 128, 512, 0, stream>>>(agg, puzzle, h, c, pb1, pb2, pb3, bih, bhh,
                                            oW, ob, ws, oh0, oh1, oc, oo);
}

// Round 17
// 372.059 us; speedup vs baseline: 1.1727x; 1.1727x over previous
//
#include <hip/hip_runtime.h>

#define NN 41472
#define NE 829440

typedef __attribute__((ext_vector_type(8))) short short8;
typedef __attribute__((ext_vector_type(4))) float f32x4;
typedef __attribute__((ext_vector_type(16))) float f32x16;
typedef __attribute__((ext_vector_type(4))) float float4v;
typedef __attribute__((ext_vector_type(4))) unsigned u32x4;

// ---- ws layout (bytes) ----
#define FLG_OFF   0
#define AGG_OFF   256
#define AGG_BYTES 15925248               // NN*96*4
#define W1F_OFF   (AGG_OFF + AGG_BYTES)  // msg W1 32x32 frags: 13*3*1024 = 39936
#define W2F_OFF   (W1F_OFF + 39936)
#define W3F_OFF   (W2F_OFF + 18432)
#define P1F_OFF   (W3F_OFF + 18432)
#define P2F_OFF   (P1F_OFF + 24576)
#define P3F_OFF   (P2F_OFF + 18432)
#define IHF_OFF   (P3F_OFF + 18432)
#define HHF_OFF   (IHF_OFF + 73728)
#define NB16_OFF  (HHF_OFF + 73728)      // nodes bf16: NN*96*2 = 7962624
#define CUR_OFF   (NB16_OFF + 7962624)   // counts/cursors: NN*4 = 165888
#define BSUM_OFF  (CUR_OFF + 165888)     // 41 block sums
#define SRT_OFF   (BSUM_OFF + 256)       // sorted (src,dst): NE*8 = 6635520
#define SID_OFF   (SRT_OFF + 6635520)    // (unused slot) NE*4
#define EFB_OFF   (SID_OFF + 3317760)    // sorted ef bf16: NE*16*2 = 26542080
#define WS_NEED   (EFB_OFF + 26542080)   // ~60.9 MB (proven available)

static __device__ __forceinline__ float bf2f(short s) {
  unsigned u = ((unsigned)(unsigned short)s) << 16;
  return __builtin_bit_cast(float, u);
}
static __device__ __forceinline__ short f2bf(float f) {
  unsigned u = __builtin_bit_cast(unsigned, f);
  unsigned r = (u + 0x7fffu + ((u >> 16) & 1u)) >> 16;
  return (short)r;
}
static __device__ __forceinline__ unsigned cvtpk(float lo, float hi) {
  unsigned r;
  asm("v_cvt_pk_bf16_f32 %0, %1, %2" : "=v"(r) : "v"(lo), "v"(hi));
  return r;
}
static __device__ __forceinline__ f32x4 fzero() { f32x4 z = {0.f, 0.f, 0.f, 0.f}; return z; }
static __device__ __forceinline__ f32x16 f16zero() {
  f32x16 z;
#pragma unroll
  for (int i = 0; i < 16; ++i) z[i] = 0.f;
  return z;
}
static __device__ __forceinline__ short8 szero() { short8 z = {0,0,0,0,0,0,0,0}; return z; }
static __device__ __forceinline__ float sigm(float x) { return 1.f / (1.f + __expf(-x)); }
static __device__ __forceinline__ float tanh_f(float x) {
  float ax = fabsf(x);
  float e  = __expf(-2.f * ax);
  float t  = (1.f - e) / (1.f + e);
  return copysignf(t, x);
}
static __device__ __forceinline__ int clampn(int v) {
  unsigned u = (unsigned)v;
  return (u < (unsigned)NN) ? v : 0;
}
static __device__ __forceinline__ float ldf(const void* base, size_t i, int f32) {
  return f32 ? ((const float*)base)[i] : bf2f(((const short*)base)[i]);
}
static __device__ __forceinline__ short8 ld8(const void* base, size_t i, int f32) {
  if (f32) {
    const float* p = (const float*)base + i;
    float4v a = *(const float4v*)p;
    float4v b = *(const float4v*)(p + 4);
    u32x4 u;
    u[0] = cvtpk(a[0], a[1]); u[1] = cvtpk(a[2], a[3]);
    u[2] = cvtpk(b[0], b[1]); u[3] = cvtpk(b[2], b[3]);
    return __builtin_bit_cast(short8, u);
  }
  return *(const short8*)((const short*)base + i);
}
static __device__ __forceinline__ short8 ldrow8(const void* base, size_t i, int f32) {
  if (f32) {
    const float* p = (const float*)base + i;
    short8 r;
#pragma unroll
    for (int j = 0; j < 8; ++j) r[j] = f2bf(p[j]);
    return r;
  }
  return *(const short8*)((const short*)base + i);
}
static __device__ __forceinline__ int ldedge(const int* e, int flat, int e64) {
  return e64 ? e[2 * flat] : e[flat];
}

// ---------------- dtype sniffing (wave-parallel) ----------------
__global__ __launch_bounds__(64) void sniff_kernel(const unsigned* __restrict__ nodes_u,
                                                   const int* __restrict__ edges_i,
                                                   int* __restrict__ flags) {
  int l = threadIdx.x;
  int votes = 0;
  for (int i = l; i < 256; i += 64) {
    unsigned u = nodes_u[i];
    int ex = (int)((u >> 23) & 0xFFu);
    if (ex >= 116 && ex <= 134) votes++;
  }
  int z = 0;
  for (int i = l; i < 128; i += 64) if (edges_i[2 * i + 1] == 0) z++;
#pragma unroll
  for (int o = 32; o; o >>= 1) { votes += __shfl_down(votes, o); z += __shfl_down(z, o); }
  if (l == 0) {
    flags[0] = (votes >= 160) ? 1 : 0;   // 1 => float arrays are fp32
    flags[1] = (z == 128) ? 1 : 0;       // 1 => edges are int64
  }
}

// zero agg (995328 float4s) + cur (NN ints), grid 3888x256
__global__ __launch_bounds__(256) void zero_all_kernel(float4v* __restrict__ agg4,
                                                       int* __restrict__ cur) {
  int i = blockIdx.x * 256 + threadIdx.x;
  agg4[i] = float4v{0.f, 0.f, 0.f, 0.f};
  if (i < NN) cur[i] = 0;
}

// ---------------- fused: edge histogram + nodes->bf16 copy (grid 3240x256) ----------------
__global__ __launch_bounds__(256) void nb16hist_kernel(const void* __restrict__ nodes,
                                                       const char* __restrict__ ws,
                                                       short8* __restrict__ out,
                                                       const int* __restrict__ edges,
                                                       int* __restrict__ cnt) {
  const int f32 = ((const int*)(ws + FLG_OFF))[0];
  const int e64 = ((const int*)(ws + FLG_OFF))[1];
  int gid = blockIdx.x * 256 + threadIdx.x;
  int s = clampn(ldedge(edges, 2 * gid, e64));
  atomicAdd(&cnt[s], 1);
  if (gid < NN * 96 / 8) out[gid] = ld8(nodes, (size_t)gid * 8, f32);
}

__global__ __launch_bounds__(1024) void scan_local_kernel(int* __restrict__ cnt,
                                                          int* __restrict__ bsum) {
  __shared__ int tmp[1024];
  const int t = threadIdx.x;
  const int i = blockIdx.x * 1024 + t;
  int v = (i < NN) ? cnt[i] : 0;
  tmp[t] = v;
  __syncthreads();
  for (int ofs = 1; ofs < 1024; ofs <<= 1) {
    int x = (t >= ofs) ? tmp[t - ofs] : 0;
    __syncthreads();
    tmp[t] += x;
    __syncthreads();
  }
  if (i < NN) cnt[i] = tmp[t] - v;   // block-local exclusive
  if (t == 1023) bsum[blockIdx.x] = tmp[1023];
}

// single-wave exclusive scan over <=64 block sums
__global__ __launch_bounds__(64) void scan_tops_kernel(int* __restrict__ bsum, int nb) {
  int l = threadIdx.x;
  int v = (l < nb) ? bsum[l] : 0;
  int x = v;
#pragma unroll
  for (int o = 1; o < 64; o <<= 1) {
    int y = __shfl_up(x, o);
    if (l >= o) x += y;
  }
  if (l < nb) bsum[l] = x - v;
}

__global__ __launch_bounds__(1024) void scan_add_kernel(int* __restrict__ cnt,
                                                        const int* __restrict__ bsum) {
  int i = blockIdx.x * 1024 + threadIdx.x;
  if (i < NN) cnt[i] += bsum[blockIdx.x];
}

// scatter + pre-permute ef into sorted order as bf16
__global__ __launch_bounds__(256) void scatter_kernel(const int* __restrict__ edges,
                                                      const void* __restrict__ ef,
                                                      const char* __restrict__ ws,
                                                      int* __restrict__ cur,
                                                      int2* __restrict__ sdst,
                                                      short* __restrict__ efb) {
  const int f32 = ((const int*)(ws + FLG_OFF))[0];
  const int e64 = ((const int*)(ws + FLG_OFF))[1];
  int e = blockIdx.x * 256 + threadIdx.x;
  int s = clampn(ldedge(edges, 2 * e, e64));
  int d = clampn(ldedge(edges, 2 * e + 1, e64));
  int pos = atomicAdd(&cur[s], 1);
  sdst[pos] = make_int2(s, d);
  short8 lo = ld8(ef, (size_t)e * 16, f32);
  short8 hi = ld8(ef, (size_t)e * 16 + 8, f32);
  *(short8*)(efb + (size_t)pos * 16) = lo;
  *(short8*)(efb + (size_t)pos * 16 + 8) = hi;
}

// ---------------- weight relayout (natural layouts) ----------------
// fmt32 (32x32x16): elem j of lane l = W[ks*16+(l>>5)*8+j][nt*32+(l&31)]
// fmt16 (16x16x32): elem j of lane l = W[ks*32+(l>>4)*8+j][nt*16+(l&15)]
__global__ __launch_bounds__(64) void relayout_kernel(
    const void* __restrict__ mW1, const void* __restrict__ mW2, const void* __restrict__ mW3,
    const void* __restrict__ pW1, const void* __restrict__ pW2, const void* __restrict__ pW3,
    const void* __restrict__ Wih, const void* __restrict__ Whh, char* __restrict__ ws)
{
  const int f32 = ((const int*)(ws + FLG_OFF))[0];
  int c = blockIdx.x;
  int l = threadIdx.x;
  const void* W; int K, NOUT, NT, fmt32; size_t off;
  if (c < 39)       {          W = mW1; K = 208; NOUT = 96;  NT = 3;  off = W1F_OFF; fmt32 = 1; }
  else if (c < 57)  { c -= 39;  W = mW2; K = 96;  NOUT = 96;  NT = 3;  off = W2F_OFF; fmt32 = 1; }
  else if (c < 75)  { c -= 57;  W = mW3; K = 96;  NOUT = 96;  NT = 3;  off = W3F_OFF; fmt32 = 1; }
  else if (c < 99)  { c -= 75;  W = pW1; K = 112; NOUT = 96;  NT = 6;  off = P1F_OFF; fmt32 = 0; }
  else if (c < 117) { c -= 99;  W = pW2; K = 96;  NOUT = 96;  NT = 6;  off = P2F_OFF; fmt32 = 0; }
  else if (c < 135) { c -= 117; W = pW3; K = 96;  NOUT = 96;  NT = 6;  off = P3F_OFF; fmt32 = 0; }
  else if (c < 207) { c -= 135; W = Wih; K = 96;  NOUT = 384; NT = 24; off = IHF_OFF; fmt32 = 0; }
  else              { c -= 207; W = Whh; K = 96;  NOUT = 384; NT = 24; off = HHF_OFF; fmt32 = 0; }
  int ks = c / NT, nt = c % NT;
  short8 v;
#pragma unroll
  for (int j = 0; j < 8; ++j) {
    int k, n;
    if (fmt32) { k = ks * 16 + (l >> 5) * 8 + j; n = nt * 32 + (l & 31); }
    else       { k = ks * 32 + (l >> 4) * 8 + j; n = nt * 16 + (l & 15); }
    v[j] = (k < K) ? f2bf(ldf(W, (size_t)k * NOUT + n, f32)) : (short)0;
  }
  short8* dst = (short8*)(ws + off);
  dst[c * 64 + l] = v;
}

// ---------------- edge message MLP (w2+w3 LDS-staged; paired-lane run merge) ----------------
// 256 threads = 4 waves, 32 edges/wave, contiguous chunks of 128-edge batches.
// LDS: w2f (18KB) + w3f (18KB) + act (26.6KB) = 62KB -> 2 blocks/CU.
template<int SORTED>
__global__ __launch_bounds__(256, 2) void edge_kernel(
    const void* __restrict__ nodes, const void* __restrict__ ef,
    const int* __restrict__ edges,
    const void* __restrict__ b1, const void* __restrict__ b2, const void* __restrict__ b3,
    const char* __restrict__ ws, float* __restrict__ agg)
{
  __shared__ __align__(16) short w2f[9216];
  __shared__ __align__(16) short w3f[9216];
  __shared__ __align__(16) short act[4][3328];

  const int f32 = ((const int*)(ws + FLG_OFF))[0];
  const int e64 = ((const int*)(ws + FLG_OFF))[1];
  const short* nb16 = (const short*)(ws + NB16_OFF);
  const int2*  sdst = (const int2*)(ws + SRT_OFF);
  const short* efb  = (const short*)(ws + EFB_OFF);

  {
    const short8* s2 = (const short8*)(ws + W2F_OFF);
    const short8* s3 = (const short8*)(ws + W3F_OFF);
    short8* d2 = (short8*)w2f;
    short8* d3 = (short8*)w3f;
    for (int i = threadIdx.x; i < 1152; i += 256) d2[i] = s2[i];
    for (int i = threadIdx.x; i < 1152; i += 256) d3[i] = s3[i];
  }
  __syncthreads();

  const int wv  = threadIdx.x >> 6;
  const int l   = threadIdx.x & 63;
  const int e31 = l & 31;
  const int hi  = l >> 5;
  short* aw = act[wv];
  const short8* w1g = (const short8*)(ws + W1F_OFF);

  const float B1[3] = {ldf(b1, e31, f32), ldf(b1, 32 + e31, f32), ldf(b1, 64 + e31, f32)};
  const float B2[3] = {ldf(b2, e31, f32), ldf(b2, 32 + e31, f32), ldf(b2, 64 + e31, f32)};
  const float B3[3] = {ldf(b3, e31, f32), ldf(b3, 32 + e31, f32), ldf(b3, 64 + e31, f32)};

  const int nbat = NE / 128;
  const int chunk = (nbat + gridDim.x - 1) / gridDim.x;
  const int it0 = blockIdx.x * chunk;
  int it1 = it0 + chunk; if (it1 > nbat) it1 = nbat;

  for (int it = it0; it < it1; ++it) {
    const int base = it * 128 + wv * 32;
    const int eL = base + e31;
    int src, dst;
    if (SORTED) {
      int2 sd = sdst[eL];
      src = clampn(sd.x); dst = clampn(sd.y);
    } else {
      src = clampn(ldedge(edges, 2 * eL, e64));
      dst = clampn(ldedge(edges, 2 * eL + 1, e64));
    }

    f32x16 a0 = f16zero(), a1 = f16zero(), a2 = f16zero();

    // ---- L1: K = 208 = 6ks src | 6ks dst | 1ks ef ----
#pragma unroll
    for (int ks = 0; ks < 6; ++ks) {
      short8 a = SORTED ? *(const short8*)(nb16 + (size_t)src * 96 + ks * 16 + hi * 8)
                        : ld8(nodes, (size_t)src * 96 + ks * 16 + hi * 8, f32);
      a0 = __builtin_amdgcn_mfma_f32_32x32x16_bf16(a, w1g[(ks * 3 + 0) * 64 + l], a0, 0, 0, 0);
      a1 = __builtin_amdgcn_mfma_f32_32x32x16_bf16(a, w1g[(ks * 3 + 1) * 64 + l], a1, 0, 0, 0);
      a2 = __builtin_amdgcn_mfma_f32_32x32x16_bf16(a, w1g[(ks * 3 + 2) * 64 + l], a2, 0, 0, 0);
    }
#pragma unroll
    for (int ks = 6; ks < 12; ++ks) {
      short8 a = SORTED ? *(const short8*)(nb16 + (size_t)dst * 96 + (ks - 6) * 16 + hi * 8)
                        : ld8(nodes, (size_t)dst * 96 + (ks - 6) * 16 + hi * 8, f32);
      a0 = __builtin_amdgcn_mfma_f32_32x32x16_bf16(a, w1g[(ks * 3 + 0) * 64 + l], a0, 0, 0, 0);
      a1 = __builtin_amdgcn_mfma_f32_32x32x16_bf16(a, w1g[(ks * 3 + 1) * 64 + l], a1, 0, 0, 0);
      a2 = __builtin_amdgcn_mfma_f32_32x32x16_bf16(a, w1g[(ks * 3 + 2) * 64 + l], a2, 0, 0, 0);
    }
    {
      short8 a = SORTED ? *(const short8*)(efb + (size_t)eL * 16 + hi * 8)
                        : ld8(ef, (size_t)eL * 16 + hi * 8, f32);
      a0 = __builtin_amdgcn_mfma_f32_32x32x16_bf16(a, w1g[(12 * 3 + 0) * 64 + l], a0, 0, 0, 0);
      a1 = __builtin_amdgcn_mfma_f32_32x32x16_bf16(a, w1g[(12 * 3 + 1) * 64 + l], a1, 0, 0, 0);
      a2 = __builtin_amdgcn_mfma_f32_32x32x16_bf16(a, w1g[(12 * 3 + 2) * 64 + l], a2, 0, 0, 0);
    }
#pragma unroll
    for (int r = 0; r < 16; ++r) {
      int row = (r & 3) + 8 * (r >> 2) + 4 * hi;
      aw[row * 104 +  0 + e31] = f2bf(fmaxf(a0[r] + B1[0], 0.f));
      aw[row * 104 + 32 + e31] = f2bf(fmaxf(a1[r] + B1[1], 0.f));
      aw[row * 104 + 64 + e31] = f2bf(fmaxf(a2[r] + B1[2], 0.f));
    }
    asm volatile("s_waitcnt lgkmcnt(0)" ::: "memory");
    __builtin_amdgcn_sched_barrier(0);

    // ---- L2 (weights from LDS) ----
    f32x16 c0 = f16zero(), c1 = f16zero(), c2 = f16zero();
#pragma unroll
    for (int ks = 0; ks < 6; ++ks) {
      short8 a = *(const short8*)&aw[e31 * 104 + ks * 16 + hi * 8];
      c0 = __builtin_amdgcn_mfma_f32_32x32x16_bf16(a, *(const short8*)&w2f[((ks * 3 + 0) * 64 + l) * 8], c0, 0, 0, 0);
      c1 = __builtin_amdgcn_mfma_f32_32x32x16_bf16(a, *(const short8*)&w2f[((ks * 3 + 1) * 64 + l) * 8], c1, 0, 0, 0);
      c2 = __builtin_amdgcn_mfma_f32_32x32x16_bf16(a, *(const short8*)&w2f[((ks * 3 + 2) * 64 + l) * 8], c2, 0, 0, 0);
    }
#pragma unroll
    for (int r = 0; r < 16; ++r) {
      int row = (r & 3) + 8 * (r >> 2) + 4 * hi;
      aw[row * 104 +  0 + e31] = f2bf(fmaxf(c0[r] + B2[0], 0.f));
      aw[row * 104 + 32 + e31] = f2bf(fmaxf(c1[r] + B2[1], 0.f));
      aw[row * 104 + 64 + e31] = f2bf(fmaxf(c2[r] + B2[2], 0.f));
    }
    asm volatile("s_waitcnt lgkmcnt(0)" ::: "memory");
    __builtin_amdgcn_sched_barrier(0);

    // ---- L3 (weights from LDS) ----
    f32x16 d0 = f16zero(), d1 = f16zero(), d2 = f16zero();
#pragma unroll
    for (int ks = 0; ks < 6; ++ks) {
      short8 a = *(const short8*)&aw[e31 * 104 + ks * 16 + hi * 8];
      d0 = __builtin_amdgcn_mfma_f32_32x32x16_bf16(a, *(const short8*)&w3f[((ks * 3 + 0) * 64 + l) * 8], d0, 0, 0, 0);
      d1 = __builtin_amdgcn_mfma_f32_32x32x16_bf16(a, *(const short8*)&w3f[((ks * 3 + 1) * 64 + l) * 8], d1, 0, 0, 0);
      d2 = __builtin_amdgcn_mfma_f32_32x32x16_bf16(a, *(const short8*)&w3f[((ks * 3 + 2) * 64 + l) * 8], d2, 0, 0, 0);
    }
    asm volatile("s_waitcnt lgkmcnt(0)" ::: "memory");
    __builtin_amdgcn_sched_barrier(0);

    // ---- segment-sum by src ----
    if (SORTED) {
      // Paired-lane full-window merge: lanes (l, l^32) share column e31 and
      // together own all 32 contiguous sorted edges. Exchange fragment values
      // (static reg index) so both lanes see row r's value; hi=0 lane merges
      // runs across the sorted 32 rows and emits one atomic trio per run.
      float s0 = 0.f, s1 = 0.f, s2 = 0.f;
      int cu = -1, cnt = 0;
#pragma unroll
      for (int g = 0; g < 8; ++g) {
#pragma unroll
        for (int j = 0; j < 4; ++j) {
          const int reg = (g >> 1) * 4 + j;      // fragment reg holding row 4g+j (for owner hi = g&1)
          float t0 = d0[reg], t1 = d1[reg], t2 = d2[reg];
          float p0 = __shfl(t0, l ^ 32, 64);
          float p1 = __shfl(t1, l ^ 32, 64);
          float p2 = __shfl(t2, l ^ 32, 64);
          float v0 = ((g & 1) == hi) ? t0 : p0;
          float v1 = ((g & 1) == hi) ? t1 : p1;
          float v2 = ((g & 1) == hi) ? t2 : p2;
          int nd = __shfl(src, 4 * g + j, 64);   // src of edge base + (4g+j)
          if (nd == cu) {
            s0 += v0; s1 += v1; s2 += v2; cnt++;
          } else {
            if (hi == 0 && cu >= 0) {
              atomicAdd(&agg[(size_t)cu * 96 +      e31], s0 + cnt * B3[0]);
              atomicAdd(&agg[(size_t)cu * 96 + 32 + e31], s1 + cnt * B3[1]);
              atomicAdd(&agg[(size_t)cu * 96 + 64 + e31], s2 + cnt * B3[2]);
            }
            cu = nd; s0 = v0; s1 = v1; s2 = v2; cnt = 1;
          }
        }
      }
      if (hi == 0 && cu >= 0) {
        atomicAdd(&agg[(size_t)cu * 96 +      e31], s0 + cnt * B3[0]);
        atomicAdd(&agg[(size_t)cu * 96 + 32 + e31], s1 + cnt * B3[1]);
        atomicAdd(&agg[(size_t)cu * 96 + 64 + e31], s2 + cnt * B3[2]);
      }
    } else {
#pragma unroll
      for (int r = 0; r < 16; ++r) {
        int row = (r & 3) + 8 * (r >> 2) + 4 * hi;
        int s = clampn(ldedge(edges, 2 * (base + row), e64));
        atomicAdd(&agg[(size_t)s * 96 +      e31], d0[r] + B3[0]);
        atomicAdd(&agg[(size_t)s * 96 + 32 + e31], d1[r] + B3[1]);
        atomicAdd(&agg[(size_t)s * 96 + 64 + e31], d2[r] + B3[2]);
      }
    }
  }
}

// ---------------- node: post-MLP + LSTM + fused output head ----------------
__global__ __launch_bounds__(512, 1) void node_kernel(
    const float* __restrict__ agg, const void* __restrict__ puzzle,
    const void* __restrict__ h, const void* __restrict__ c,
    const void* __restrict__ pb1, const void* __restrict__ pb2, const void* __restrict__ pb3,
    const void* __restrict__ bih, const void* __restrict__ bhh,
    const void* __restrict__ oW, const void* __restrict__ ob,
    const char* __restrict__ ws,
    float* __restrict__ oh0, float* __restrict__ oh1, float* __restrict__ oc,
    float* __restrict__ oo)
{
  __shared__ __align__(16) short p2f[9216];
  __shared__ __align__(16) short p3f[9216];
  __shared__ __align__(16) short act[8][16][104];

  const int f32 = ((const int*)(ws + FLG_OFF))[0];

  {
    const short8* s2 = (const short8*)(ws + P2F_OFF);
    const short8* s3 = (const short8*)(ws + P3F_OFF);
    short8* d2 = (short8*)p2f;
    short8* d3 = (short8*)p3f;
    for (int i = threadIdx.x; i < 1152; i += 512) d2[i] = s2[i];
    for (int i = threadIdx.x; i < 1152; i += 512) d3[i] = s3[i];
  }
  __syncthreads();

  const int wv = threadIdx.x >> 6;
  const int l  = threadIdx.x & 63;
  const int lg = l >> 4, lr = l & 15;
  const int n0 = blockIdx.x * 128 + wv * 16;
  const int row = n0 + lr;

  const short8* p1g = (const short8*)(ws + P1F_OFF);
  const short8* ihg = (const short8*)(ws + IHF_OFF);
  const short8* hhg = (const short8*)(ws + HHF_OFF);

  f32x4 acc[6];
#pragma unroll
  for (int nt = 0; nt < 6; ++nt) acc[nt] = fzero();

#pragma unroll
  for (int ks = 0; ks < 3; ++ks) {
    const float* p = agg + (size_t)row * 96 + ks * 32 + lg * 8;
    short8 ahi, alo;
#pragma unroll
    for (int j = 0; j < 8; ++j) {
      float v = p[j];
      short hiq = f2bf(v);
      ahi[j] = hiq;
      alo[j] = f2bf(v - bf2f(hiq));
    }
#pragma unroll
    for (int nt = 0; nt < 6; ++nt) {
      short8 b = p1g[(ks * 6 + nt) * 64 + l];
      acc[nt] = __builtin_amdgcn_mfma_f32_16x16x32_bf16(ahi, b, acc[nt], 0, 0, 0);
      acc[nt] = __builtin_amdgcn_mfma_f32_16x16x32_bf16(alo, b, acc[nt], 0, 0, 0);
    }
  }
  {
    short8 a;
    if (lg < 2) a = ldrow8(puzzle, (size_t)row * 16 + lg * 8, f32);
    else        a = szero();
#pragma unroll
    for (int nt = 0; nt < 6; ++nt) {
      short8 b = p1g[(3 * 6 + nt) * 64 + l];
      acc[nt] = __builtin_amdgcn_mfma_f32_16x16x32_bf16(a, b, acc[nt], 0, 0, 0);
    }
  }
#pragma unroll
  for (int nt = 0; nt < 6; ++nt) {
    float bb = ldf(pb1, nt * 16 + lr, f32);
#pragma unroll
    for (int r = 0; r < 4; ++r) {
      float v = fmaxf(acc[nt][r] + bb, 0.f);
      act[wv][lg * 4 + r][nt * 16 + lr] = f2bf(v);
    }
    acc[nt] = fzero();
  }
  __syncthreads();

#pragma unroll
  for (int ks = 0; ks < 3; ++ks) {
    short8 a = *(const short8*)&act[wv][lr][ks * 32 + lg * 8];
#pragma unroll
    for (int nt = 0; nt < 6; ++nt) {
      short8 b = *(const short8*)&p2f[((ks * 6 + nt) * 64 + l) * 8];
      acc[nt] = __builtin_amdgcn_mfma_f32_16x16x32_bf16(a, b, acc[nt], 0, 0, 0);
    }
  }
  __syncthreads();
#pragma unroll
  for (int nt = 0; nt < 6; ++nt) {
    float bb = ldf(pb2, nt * 16 + lr, f32);
#pragma unroll
    for (int r = 0; r < 4; ++r) {
      float v = fmaxf(acc[nt][r] + bb, 0.f);
      act[wv][lg * 4 + r][nt * 16 + lr] = f2bf(v);
    }
    acc[nt] = fzero();
  }
  __syncthreads();

#pragma unroll
  for (int ks = 0; ks < 3; ++ks) {
    short8 a = *(const short8*)&act[wv][lr][ks * 32 + lg * 8];
#pragma unroll
    for (int nt = 0; nt < 6; ++nt) {
      short8 b = *(const short8*)&p3f[((ks * 6 + nt) * 64 + l) * 8];
      acc[nt] = __builtin_amdgcn_mfma_f32_16x16x32_bf16(a, b, acc[nt], 0, 0, 0);
    }
  }
  __syncthreads();
#pragma unroll
  for (int nt = 0; nt < 6; ++nt) {
    float bb = ldf(pb3, nt * 16 + lr, f32);
#pragma unroll
    for (int r = 0; r < 4; ++r) {
      act[wv][lg * 4 + r][nt * 16 + lr] = f2bf(acc[nt][r] + bb);
    }
  }
  __syncthreads();

  f32x4 g[24];
#pragma unroll
  for (int nt = 0; nt < 24; ++nt) g[nt] = fzero();
#pragma unroll
  for (int ks = 0; ks < 3; ++ks) {
    short8 ax = *(const short8*)&act[wv][lr][ks * 32 + lg * 8];
    short8 ah = ldrow8(h, (size_t)row * 96 + ks * 32 + lg * 8, f32);
#pragma unroll
    for (int nt = 0; nt < 24; ++nt) {
      short8 bi = ihg[(ks * 24 + nt) * 64 + l];
      g[nt] = __builtin_amdgcn_mfma_f32_16x16x32_bf16(ax, bi, g[nt], 0, 0, 0);
      short8 bh = hhg[(ks * 24 + nt) * 64 + l];
      g[nt] = __builtin_amdgcn_mfma_f32_16x16x32_bf16(ah, bh, g[nt], 0, 0, 0);
    }
  }

  // LSTM elementwise + fp32 writeback; h_new also stashed (bf16) into act for the head
#pragma unroll
  for (int nt = 0; nt < 6; ++nt) {
    int col = nt * 16 + lr;
    float bi_i = ldf(bih, col, f32)       + ldf(bhh, col, f32);
    float bi_f = ldf(bih, 96 + col, f32)  + ldf(bhh, 96 + col, f32);
    float bi_g = ldf(bih, 192 + col, f32) + ldf(bhh, 192 + col, f32);
    float bi_o = ldf(bih, 288 + col, f32) + ldf(bhh, 288 + col, f32);
#pragma unroll
    for (int r = 0; r < 4; ++r) {
      int node = n0 + lg * 4 + r;
      float iv = g[nt][r]      + bi_i;
      float fv = g[nt + 6][r]  + bi_f;
      float gv = g[nt + 12][r] + bi_g;
      float ov = g[nt + 18][r] + bi_o;
      float cv = ldf(c, (size_t)node * 96 + col, f32);
      float cn = sigm(fv) * cv + sigm(iv) * tanh_f(gv);
      float hn = sigm(ov) * tanh_f(cn);
      oh0[(size_t)node * 96 + col] = hn;
      oh1[(size_t)node * 96 + col] = hn;
      oc [(size_t)node * 96 + col] = cn;
      act[wv][lg * 4 + r][col] = f2bf(hn);
    }
  }
  __syncthreads();

  // ---- fused head: out[node][o] = ob[o] + h_new . oW[:,o] (128 nodes x 10 outs) ----
  const int nb0 = blockIdx.x * 128;
  for (int idx = threadIdx.x; idx < 1280; idx += 512) {
    int node16 = idx / 10;     // 0..127
    int o = idx - node16 * 10;
    const short* hrow = &act[node16 >> 4][node16 & 15][0];
    float a2 = ldf(ob, o, f32);
    for (int k = 0; k < 96; ++k)
      a2 = fmaf(bf2f(hrow[k]), ldf(oW, (size_t)k * 10 + o, f32), a2);
    oo[(size_t)(nb0 + node16) * 10 + o] = a2;
  }
}

extern "C" void kernel_launch(void* const* d_in, const int* in_sizes, int n_in,
                              void* d_out, int out_size, void* d_ws, size_t ws_size,
                              hipStream_t stream)
{
  const void* puzzle = d_in[0];
  const void* nodes  = d_in[1];
  const void* ef     = d_in[2];
  const void* h      = d_in[3];
  const void* c      = d_in[4];
  const int*  edges  = (const int*)d_in[5];
  const void* mW1 = d_in[6];  const void* mb1 = d_in[7];
  const void* mW2 = d_in[8];  const void* mb2 = d_in[9];
  const void* mW3 = d_in[10]; const void* mb3 = d_in[11];
  const void* pW1 = d_in[12]; const void* pb1 = d_in[13];
  const void* pW2 = d_in[14]; const void* pb2 = d_in[15];
  const void* pW3 = d_in[16]; const void* pb3 = d_in[17];
  const void* Wih = d_in[18]; const void* bih = d_in[19];
  const void* Whh = d_in[20]; const void* bhh = d_in[21];
  const void* oW  = d_in[22]; const void* ob  = d_in[23];

  char*  ws  = (char*)d_ws;
  int* flags = (int*)(ws + FLG_OFF);
  float* agg = (float*)(ws + AGG_OFF);
  int* cur = (int*)(ws + CUR_OFF);
  float* out = (float*)d_out;
  float* oh0 = out;
  float* oh1 = out + (size_t)NN * 96;
  float* oc  = out + (size_t)2 * NN * 96;
  float* oo  = out + (size_t)3 * NN * 96;

  sniff_kernel<<<1, 64, 0, stream>>>((const unsigned*)nodes, edges, flags);
  zero_all_kernel<<<3888, 256, 0, stream>>>((float4v*)agg, cur);
  relayout_kernel<<<279, 64, 0, stream>>>(mW1, mW2, mW3, pW1, pW2, pW3, Wih, Whh, ws);

  if (ws_size >= (size_t)WS_NEED) {
    int* bsum = (int*)(ws + BSUM_OFF);
    int2* sdst = (int2*)(ws + SRT_OFF);
    short* efb = (short*)(ws + EFB_OFF);
    const int nb = (NN + 1023) / 1024;   // 41

    nb16hist_kernel<<<NE / 256, 256, 0, stream>>>(nodes, ws, (short8*)(ws + NB16_OFF),
                                                  edges, cur);
    scan_local_kernel<<<nb, 1024, 0, stream>>>(cur, bsum);
    scan_tops_kernel<<<1, 64, 0, stream>>>(bsum, nb);
    scan_add_kernel<<<nb, 1024, 0, stream>>>(cur, bsum);
    scatter_kernel<<<NE / 256, 256, 0, stream>>>(edges, ef, ws, cur, sdst, efb);
    edge_kernel<1><<<512, 256, 0, stream>>>(nodes, ef, edges, mb1, mb2, mb3, ws, agg);
  } else {
    edge_kernel<0><<<512, 256, 0, stream>>>(nodes, ef, edges, mb1, mb2, mb3, ws, agg);
  }

  node_kernel<<<NN / 128, 512, 0, stream>>>(agg, puzzle, h, c, pb1, pb2, pb3, bih, bhh,
                                            oW, ob, ws, oh0, oh1, oc, oo);
}

// Round 18
// 316.822 us; speedup vs baseline: 1.3771x; 1.1743x over previous
//
#include <hip/hip_runtime.h>

#define NN 41472
#define NE 829440

typedef __attribute__((ext_vector_type(8))) short short8;
typedef __attribute__((ext_vector_type(4))) float f32x4;
typedef __attribute__((ext_vector_type(16))) float f32x16;
typedef __attribute__((ext_vector_type(4))) float float4v;
typedef __attribute__((ext_vector_type(4))) unsigned u32x4;

#define WAVESYNC() do { asm volatile("s_waitcnt lgkmcnt(0)" ::: "memory"); \
                        __builtin_amdgcn_sched_barrier(0); } while (0)

// ---- ws layout (bytes) ----
#define FLG_OFF   0
#define AGG_OFF   256
#define AGG_BYTES 15925248               // NN*96*4
#define W1F_OFF   (AGG_OFF + AGG_BYTES)  // msg W1 32x32 frags: 13*3*1024 = 39936
#define W2F_OFF   (W1F_OFF + 39936)
#define W3F_OFF   (W2F_OFF + 18432)
#define P1F_OFF   (W3F_OFF + 18432)
#define P2F_OFF   (P1F_OFF + 24576)
#define P3F_OFF   (P2F_OFF + 18432)
#define IHF_OFF   (P3F_OFF + 18432)
#define HHF_OFF   (IHF_OFF + 73728)
#define NB16_OFF  (HHF_OFF + 73728)      // nodes bf16: NN*96*2 = 7962624
#define CUR_OFF   (NB16_OFF + 7962624)   // counts/cursors: NN*4 = 165888
#define BSUM_OFF  (CUR_OFF + 165888)     // 41 block sums
#define SRT_OFF   (BSUM_OFF + 256)       // sorted (src,dst): NE*8 = 6635520
#define SID_OFF   (SRT_OFF + 6635520)    // (unused slot) NE*4
#define EFB_OFF   (SID_OFF + 3317760)    // sorted ef bf16: NE*16*2 = 26542080
#define WS_NEED   (EFB_OFF + 26542080)   // ~60.9 MB (proven available)

static __device__ __forceinline__ float bf2f(short s) {
  unsigned u = ((unsigned)(unsigned short)s) << 16;
  return __builtin_bit_cast(float, u);
}
static __device__ __forceinline__ short f2bf(float f) {
  unsigned u = __builtin_bit_cast(unsigned, f);
  unsigned r = (u + 0x7fffu + ((u >> 16) & 1u)) >> 16;
  return (short)r;
}
static __device__ __forceinline__ unsigned cvtpk(float lo, float hi) {
  unsigned r;
  asm("v_cvt_pk_bf16_f32 %0, %1, %2" : "=v"(r) : "v"(lo), "v"(hi));
  return r;
}
static __device__ __forceinline__ f32x4 fzero() { f32x4 z = {0.f, 0.f, 0.f, 0.f}; return z; }
static __device__ __forceinline__ f32x16 f16zero() {
  f32x16 z;
#pragma unroll
  for (int i = 0; i < 16; ++i) z[i] = 0.f;
  return z;
}
static __device__ __forceinline__ short8 szero() { short8 z = {0,0,0,0,0,0,0,0}; return z; }
static __device__ __forceinline__ float sigm(float x) { return 1.f / (1.f + __expf(-x)); }
static __device__ __forceinline__ float tanh_f(float x) {
  float ax = fabsf(x);
  float e  = __expf(-2.f * ax);
  float t  = (1.f - e) / (1.f + e);
  return copysignf(t, x);
}
static __device__ __forceinline__ int clampn(int v) {
  unsigned u = (unsigned)v;
  return (u < (unsigned)NN) ? v : 0;
}
static __device__ __forceinline__ float ldf(const void* base, size_t i, int f32) {
  return f32 ? ((const float*)base)[i] : bf2f(((const short*)base)[i]);
}
static __device__ __forceinline__ short8 ld8(const void* base, size_t i, int f32) {
  if (f32) {
    const float* p = (const float*)base + i;
    float4v a = *(const float4v*)p;
    float4v b = *(const float4v*)(p + 4);
    u32x4 u;
    u[0] = cvtpk(a[0], a[1]); u[1] = cvtpk(a[2], a[3]);
    u[2] = cvtpk(b[0], b[1]); u[3] = cvtpk(b[2], b[3]);
    return __builtin_bit_cast(short8, u);
  }
  return *(const short8*)((const short*)base + i);
}
static __device__ __forceinline__ short8 ldrow8(const void* base, size_t i, int f32) {
  if (f32) {
    const float* p = (const float*)base + i;
    short8 r;
#pragma unroll
    for (int j = 0; j < 8; ++j) r[j] = f2bf(p[j]);
    return r;
  }
  return *(const short8*)((const short*)base + i);
}
static __device__ __forceinline__ int ldedge(const int* e, int flat, int e64) {
  return e64 ? e[2 * flat] : e[flat];
}

// ---------------- dtype sniffing (wave-parallel) ----------------
__global__ __launch_bounds__(64) void sniff_kernel(const unsigned* __restrict__ nodes_u,
                                                   const int* __restrict__ edges_i,
                                                   int* __restrict__ flags) {
  int l = threadIdx.x;
  int votes = 0;
  for (int i = l; i < 256; i += 64) {
    unsigned u = nodes_u[i];
    int ex = (int)((u >> 23) & 0xFFu);
    if (ex >= 116 && ex <= 134) votes++;
  }
  int z = 0;
  for (int i = l; i < 128; i += 64) if (edges_i[2 * i + 1] == 0) z++;
#pragma unroll
  for (int o = 32; o; o >>= 1) { votes += __shfl_down(votes, o); z += __shfl_down(z, o); }
  if (l == 0) {
    flags[0] = (votes >= 160) ? 1 : 0;   // 1 => float arrays are fp32
    flags[1] = (z == 128) ? 1 : 0;       // 1 => edges are int64
  }
}

// zero agg (995328 float4s) + cur (NN ints), grid 3888x256
__global__ __launch_bounds__(256) void zero_all_kernel(float4v* __restrict__ agg4,
                                                       int* __restrict__ cur) {
  int i = blockIdx.x * 256 + threadIdx.x;
  agg4[i] = float4v{0.f, 0.f, 0.f, 0.f};
  if (i < NN) cur[i] = 0;
}

// ---------------- fused: edge histogram + nodes->bf16 copy (grid 3240x256) ----------------
__global__ __launch_bounds__(256) void nb16hist_kernel(const void* __restrict__ nodes,
                                                       const char* __restrict__ ws,
                                                       short8* __restrict__ out,
                                                       const int* __restrict__ edges,
                                                       int* __restrict__ cnt) {
  const int f32 = ((const int*)(ws + FLG_OFF))[0];
  const int e64 = ((const int*)(ws + FLG_OFF))[1];
  int gid = blockIdx.x * 256 + threadIdx.x;
  int s = clampn(ldedge(edges, 2 * gid, e64));
  atomicAdd(&cnt[s], 1);
  if (gid < NN * 96 / 8) out[gid] = ld8(nodes, (size_t)gid * 8, f32);
}

__global__ __launch_bounds__(1024) void scan_local_kernel(int* __restrict__ cnt,
                                                          int* __restrict__ bsum) {
  __shared__ int tmp[1024];
  const int t = threadIdx.x;
  const int i = blockIdx.x * 1024 + t;
  int v = (i < NN) ? cnt[i] : 0;
  tmp[t] = v;
  __syncthreads();
  for (int ofs = 1; ofs < 1024; ofs <<= 1) {
    int x = (t >= ofs) ? tmp[t - ofs] : 0;
    __syncthreads();
    tmp[t] += x;
    __syncthreads();
  }
  if (i < NN) cnt[i] = tmp[t] - v;   // block-local exclusive
  if (t == 1023) bsum[blockIdx.x] = tmp[1023];
}

// single-wave exclusive scan over <=64 block sums
__global__ __launch_bounds__(64) void scan_tops_kernel(int* __restrict__ bsum, int nb) {
  int l = threadIdx.x;
  int v = (l < nb) ? bsum[l] : 0;
  int x = v;
#pragma unroll
  for (int o = 1; o < 64; o <<= 1) {
    int y = __shfl_up(x, o);
    if (l >= o) x += y;
  }
  if (l < nb) bsum[l] = x - v;
}

__global__ __launch_bounds__(1024) void scan_add_kernel(int* __restrict__ cnt,
                                                        const int* __restrict__ bsum) {
  int i = blockIdx.x * 1024 + threadIdx.x;
  if (i < NN) cnt[i] += bsum[blockIdx.x];
}

// scatter + pre-permute ef into sorted order as bf16
__global__ __launch_bounds__(256) void scatter_kernel(const int* __restrict__ edges,
                                                      const void* __restrict__ ef,
                                                      const char* __restrict__ ws,
                                                      int* __restrict__ cur,
                                                      int2* __restrict__ sdst,
                                                      short* __restrict__ efb) {
  const int f32 = ((const int*)(ws + FLG_OFF))[0];
  const int e64 = ((const int*)(ws + FLG_OFF))[1];
  int e = blockIdx.x * 256 + threadIdx.x;
  int s = clampn(ldedge(edges, 2 * e, e64));
  int d = clampn(ldedge(edges, 2 * e + 1, e64));
  int pos = atomicAdd(&cur[s], 1);
  sdst[pos] = make_int2(s, d);
  short8 lo = ld8(ef, (size_t)e * 16, f32);
  short8 hi = ld8(ef, (size_t)e * 16 + 8, f32);
  *(short8*)(efb + (size_t)pos * 16) = lo;
  *(short8*)(efb + (size_t)pos * 16 + 8) = hi;
}

// ---------------- weight relayout (natural layouts) ----------------
// fmt32 (32x32x16): elem j of lane l = W[ks*16+(l>>5)*8+j][nt*32+(l&31)]
// fmt16 (16x16x32): elem j of lane l = W[ks*32+(l>>4)*8+j][nt*16+(l&15)]
__global__ __launch_bounds__(64) void relayout_kernel(
    const void* __restrict__ mW1, const void* __restrict__ mW2, const void* __restrict__ mW3,
    const void* __restrict__ pW1, const void* __restrict__ pW2, const void* __restrict__ pW3,
    const void* __restrict__ Wih, const void* __restrict__ Whh, char* __restrict__ ws)
{
  const int f32 = ((const int*)(ws + FLG_OFF))[0];
  int c = blockIdx.x;
  int l = threadIdx.x;
  const void* W; int K, NOUT, NT, fmt32; size_t off;
  if (c < 39)       {          W = mW1; K = 208; NOUT = 96;  NT = 3;  off = W1F_OFF; fmt32 = 1; }
  else if (c < 57)  { c -= 39;  W = mW2; K = 96;  NOUT = 96;  NT = 3;  off = W2F_OFF; fmt32 = 1; }
  else if (c < 75)  { c -= 57;  W = mW3; K = 96;  NOUT = 96;  NT = 3;  off = W3F_OFF; fmt32 = 1; }
  else if (c < 99)  { c -= 75;  W = pW1; K = 112; NOUT = 96;  NT = 6;  off = P1F_OFF; fmt32 = 0; }
  else if (c < 117) { c -= 99;  W = pW2; K = 96;  NOUT = 96;  NT = 6;  off = P2F_OFF; fmt32 = 0; }
  else if (c < 135) { c -= 117; W = pW3; K = 96;  NOUT = 96;  NT = 6;  off = P3F_OFF; fmt32 = 0; }
  else if (c < 207) { c -= 135; W = Wih; K = 96;  NOUT = 384; NT = 24; off = IHF_OFF; fmt32 = 0; }
  else              { c -= 207; W = Whh; K = 96;  NOUT = 384; NT = 24; off = HHF_OFF; fmt32 = 0; }
  int ks = c / NT, nt = c % NT;
  short8 v;
#pragma unroll
  for (int j = 0; j < 8; ++j) {
    int k, n;
    if (fmt32) { k = ks * 16 + (l >> 5) * 8 + j; n = nt * 32 + (l & 31); }
    else       { k = ks * 32 + (l >> 4) * 8 + j; n = nt * 16 + (l & 15); }
    v[j] = (k < K) ? f2bf(ldf(W, (size_t)k * NOUT + n, f32)) : (short)0;
  }
  short8* dst = (short8*)(ws + off);
  dst[c * 64 + l] = v;
}

// ---------------- edge message MLP (w2+w3 LDS-staged; paired-lane run merge) ----------------
// 256 threads = 4 waves, 32 edges/wave, contiguous chunks of 128-edge batches.
// LDS: w2f (18KB) + w3f (18KB) + act (26.6KB) = 62KB -> 2 blocks/CU.
template<int SORTED>
__global__ __launch_bounds__(256, 2) void edge_kernel(
    const void* __restrict__ nodes, const void* __restrict__ ef,
    const int* __restrict__ edges,
    const void* __restrict__ b1, const void* __restrict__ b2, const void* __restrict__ b3,
    const char* __restrict__ ws, float* __restrict__ agg)
{
  __shared__ __align__(16) short w2f[9216];
  __shared__ __align__(16) short w3f[9216];
  __shared__ __align__(16) short act[4][3328];

  const int f32 = ((const int*)(ws + FLG_OFF))[0];
  const int e64 = ((const int*)(ws + FLG_OFF))[1];
  const short* nb16 = (const short*)(ws + NB16_OFF);
  const int2*  sdst = (const int2*)(ws + SRT_OFF);
  const short* efb  = (const short*)(ws + EFB_OFF);

  {
    const short8* s2 = (const short8*)(ws + W2F_OFF);
    const short8* s3 = (const short8*)(ws + W3F_OFF);
    short8* d2 = (short8*)w2f;
    short8* d3 = (short8*)w3f;
    for (int i = threadIdx.x; i < 1152; i += 256) d2[i] = s2[i];
    for (int i = threadIdx.x; i < 1152; i += 256) d3[i] = s3[i];
  }
  __syncthreads();

  const int wv  = threadIdx.x >> 6;
  const int l   = threadIdx.x & 63;
  const int e31 = l & 31;
  const int hi  = l >> 5;
  short* aw = act[wv];
  const short8* w1g = (const short8*)(ws + W1F_OFF);

  const float B1[3] = {ldf(b1, e31, f32), ldf(b1, 32 + e31, f32), ldf(b1, 64 + e31, f32)};
  const float B2[3] = {ldf(b2, e31, f32), ldf(b2, 32 + e31, f32), ldf(b2, 64 + e31, f32)};
  const float B3[3] = {ldf(b3, e31, f32), ldf(b3, 32 + e31, f32), ldf(b3, 64 + e31, f32)};

  const int nbat = NE / 128;
  const int chunk = (nbat + gridDim.x - 1) / gridDim.x;
  const int it0 = blockIdx.x * chunk;
  int it1 = it0 + chunk; if (it1 > nbat) it1 = nbat;

  for (int it = it0; it < it1; ++it) {
    const int base = it * 128 + wv * 32;
    const int eL = base + e31;
    int src, dst;
    if (SORTED) {
      int2 sd = sdst[eL];
      src = clampn(sd.x); dst = clampn(sd.y);
    } else {
      src = clampn(ldedge(edges, 2 * eL, e64));
      dst = clampn(ldedge(edges, 2 * eL + 1, e64));
    }

    f32x16 a0 = f16zero(), a1 = f16zero(), a2 = f16zero();

    // ---- L1: K = 208 = 6ks src | 6ks dst | 1ks ef ----
#pragma unroll
    for (int ks = 0; ks < 6; ++ks) {
      short8 a = SORTED ? *(const short8*)(nb16 + (size_t)src * 96 + ks * 16 + hi * 8)
                        : ld8(nodes, (size_t)src * 96 + ks * 16 + hi * 8, f32);
      a0 = __builtin_amdgcn_mfma_f32_32x32x16_bf16(a, w1g[(ks * 3 + 0) * 64 + l], a0, 0, 0, 0);
      a1 = __builtin_amdgcn_mfma_f32_32x32x16_bf16(a, w1g[(ks * 3 + 1) * 64 + l], a1, 0, 0, 0);
      a2 = __builtin_amdgcn_mfma_f32_32x32x16_bf16(a, w1g[(ks * 3 + 2) * 64 + l], a2, 0, 0, 0);
    }
#pragma unroll
    for (int ks = 6; ks < 12; ++ks) {
      short8 a = SORTED ? *(const short8*)(nb16 + (size_t)dst * 96 + (ks - 6) * 16 + hi * 8)
                        : ld8(nodes, (size_t)dst * 96 + (ks - 6) * 16 + hi * 8, f32);
      a0 = __builtin_amdgcn_mfma_f32_32x32x16_bf16(a, w1g[(ks * 3 + 0) * 64 + l], a0, 0, 0, 0);
      a1 = __builtin_amdgcn_mfma_f32_32x32x16_bf16(a, w1g[(ks * 3 + 1) * 64 + l], a1, 0, 0, 0);
      a2 = __builtin_amdgcn_mfma_f32_32x32x16_bf16(a, w1g[(ks * 3 + 2) * 64 + l], a2, 0, 0, 0);
    }
    {
      short8 a = SORTED ? *(const short8*)(efb + (size_t)eL * 16 + hi * 8)
                        : ld8(ef, (size_t)eL * 16 + hi * 8, f32);
      a0 = __builtin_amdgcn_mfma_f32_32x32x16_bf16(a, w1g[(12 * 3 + 0) * 64 + l], a0, 0, 0, 0);
      a1 = __builtin_amdgcn_mfma_f32_32x32x16_bf16(a, w1g[(12 * 3 + 1) * 64 + l], a1, 0, 0, 0);
      a2 = __builtin_amdgcn_mfma_f32_32x32x16_bf16(a, w1g[(12 * 3 + 2) * 64 + l], a2, 0, 0, 0);
    }
#pragma unroll
    for (int r = 0; r < 16; ++r) {
      int row = (r & 3) + 8 * (r >> 2) + 4 * hi;
      aw[row * 104 +  0 + e31] = f2bf(fmaxf(a0[r] + B1[0], 0.f));
      aw[row * 104 + 32 + e31] = f2bf(fmaxf(a1[r] + B1[1], 0.f));
      aw[row * 104 + 64 + e31] = f2bf(fmaxf(a2[r] + B1[2], 0.f));
    }
    WAVESYNC();

    // ---- L2 (weights from LDS) ----
    f32x16 c0 = f16zero(), c1 = f16zero(), c2 = f16zero();
#pragma unroll
    for (int ks = 0; ks < 6; ++ks) {
      short8 a = *(const short8*)&aw[e31 * 104 + ks * 16 + hi * 8];
      c0 = __builtin_amdgcn_mfma_f32_32x32x16_bf16(a, *(const short8*)&w2f[((ks * 3 + 0) * 64 + l) * 8], c0, 0, 0, 0);
      c1 = __builtin_amdgcn_mfma_f32_32x32x16_bf16(a, *(const short8*)&w2f[((ks * 3 + 1) * 64 + l) * 8], c1, 0, 0, 0);
      c2 = __builtin_amdgcn_mfma_f32_32x32x16_bf16(a, *(const short8*)&w2f[((ks * 3 + 2) * 64 + l) * 8], c2, 0, 0, 0);
    }
#pragma unroll
    for (int r = 0; r < 16; ++r) {
      int row = (r & 3) + 8 * (r >> 2) + 4 * hi;
      aw[row * 104 +  0 + e31] = f2bf(fmaxf(c0[r] + B2[0], 0.f));
      aw[row * 104 + 32 + e31] = f2bf(fmaxf(c1[r] + B2[1], 0.f));
      aw[row * 104 + 64 + e31] = f2bf(fmaxf(c2[r] + B2[2], 0.f));
    }
    WAVESYNC();

    // ---- L3 (weights from LDS) ----
    f32x16 d0 = f16zero(), d1 = f16zero(), d2 = f16zero();
#pragma unroll
    for (int ks = 0; ks < 6; ++ks) {
      short8 a = *(const short8*)&aw[e31 * 104 + ks * 16 + hi * 8];
      d0 = __builtin_amdgcn_mfma_f32_32x32x16_bf16(a, *(const short8*)&w3f[((ks * 3 + 0) * 64 + l) * 8], d0, 0, 0, 0);
      d1 = __builtin_amdgcn_mfma_f32_32x32x16_bf16(a, *(const short8*)&w3f[((ks * 3 + 1) * 64 + l) * 8], d1, 0, 0, 0);
      d2 = __builtin_amdgcn_mfma_f32_32x32x16_bf16(a, *(const short8*)&w3f[((ks * 3 + 2) * 64 + l) * 8], d2, 0, 0, 0);
    }
    WAVESYNC();

    // ---- segment-sum by src ----
    if (SORTED) {
      // Paired-lane full-window merge (r17-verified): lanes (l, l^32) share
      // column e31; exchange fragment values so hi=0 lanes merge runs across
      // all 32 contiguous sorted edges -> ~1 atomic trio per node-run.
      float s0 = 0.f, s1 = 0.f, s2 = 0.f;
      int cu = -1, cnt = 0;
#pragma unroll
      for (int g = 0; g < 8; ++g) {
#pragma unroll
        for (int j = 0; j < 4; ++j) {
          const int reg = (g >> 1) * 4 + j;
          float t0 = d0[reg], t1 = d1[reg], t2 = d2[reg];
          float p0 = __shfl(t0, l ^ 32, 64);
          float p1 = __shfl(t1, l ^ 32, 64);
          float p2 = __shfl(t2, l ^ 32, 64);
          float v0 = ((g & 1) == hi) ? t0 : p0;
          float v1 = ((g & 1) == hi) ? t1 : p1;
          float v2 = ((g & 1) == hi) ? t2 : p2;
          int nd = __shfl(src, 4 * g + j, 64);
          if (nd == cu) {
            s0 += v0; s1 += v1; s2 += v2; cnt++;
          } else {
            if (hi == 0 && cu >= 0) {
              atomicAdd(&agg[(size_t)cu * 96 +      e31], s0 + cnt * B3[0]);
              atomicAdd(&agg[(size_t)cu * 96 + 32 + e31], s1 + cnt * B3[1]);
              atomicAdd(&agg[(size_t)cu * 96 + 64 + e31], s2 + cnt * B3[2]);
            }
            cu = nd; s0 = v0; s1 = v1; s2 = v2; cnt = 1;
          }
        }
      }
      if (hi == 0 && cu >= 0) {
        atomicAdd(&agg[(size_t)cu * 96 +      e31], s0 + cnt * B3[0]);
        atomicAdd(&agg[(size_t)cu * 96 + 32 + e31], s1 + cnt * B3[1]);
        atomicAdd(&agg[(size_t)cu * 96 + 64 + e31], s2 + cnt * B3[2]);
      }
    } else {
#pragma unroll
      for (int r = 0; r < 16; ++r) {
        int row = (r & 3) + 8 * (r >> 2) + 4 * hi;
        int s = clampn(ldedge(edges, 2 * (base + row), e64));
        atomicAdd(&agg[(size_t)s * 96 +      e31], d0[r] + B3[0]);
        atomicAdd(&agg[(size_t)s * 96 + 32 + e31], d1[r] + B3[1]);
        atomicAdd(&agg[(size_t)s * 96 + 64 + e31], d2[r] + B3[2]);
      }
    }
  }
}

// ---------------- node: post-MLP + LSTM + fused head, barrier-free layers ----------------
// 256 threads = 4 waves, 16 nodes/wave (64/block), grid 648.
// act[wv] is wave-private: inter-layer deps need only lgkmcnt (edge-kernel pattern).
// LDS: p2f (18KB) + p3f (18KB) + act (13.3KB) = 49.3KB -> 3 blocks/CU.
__global__ __launch_bounds__(256, 2) void node_kernel(
    const float* __restrict__ agg, const void* __restrict__ puzzle,
    const void* __restrict__ h, const void* __restrict__ c,
    const void* __restrict__ pb1, const void* __restrict__ pb2, const void* __restrict__ pb3,
    const void* __restrict__ bih, const void* __restrict__ bhh,
    const void* __restrict__ oW, const void* __restrict__ ob,
    const char* __restrict__ ws,
    float* __restrict__ oh0, float* __restrict__ oh1, float* __restrict__ oc,
    float* __restrict__ oo)
{
  __shared__ __align__(16) short p2f[9216];
  __shared__ __align__(16) short p3f[9216];
  __shared__ __align__(16) short act[4][16][104];

  const int f32 = ((const int*)(ws + FLG_OFF))[0];

  {
    const short8* s2 = (const short8*)(ws + P2F_OFF);
    const short8* s3 = (const short8*)(ws + P3F_OFF);
    short8* d2 = (short8*)p2f;
    short8* d3 = (short8*)p3f;
    for (int i = threadIdx.x; i < 1152; i += 256) d2[i] = s2[i];
    for (int i = threadIdx.x; i < 1152; i += 256) d3[i] = s3[i];
  }
  __syncthreads();

  const int wv = threadIdx.x >> 6;
  const int l  = threadIdx.x & 63;
  const int lg = l >> 4, lr = l & 15;
  const int n0 = blockIdx.x * 64 + wv * 16;
  const int row = n0 + lr;

  const short8* p1g = (const short8*)(ws + P1F_OFF);
  const short8* ihg = (const short8*)(ws + IHF_OFF);
  const short8* hhg = (const short8*)(ws + HHF_OFF);

  f32x4 acc[6];
#pragma unroll
  for (int nt = 0; nt < 6; ++nt) acc[nt] = fzero();

  // post L1: K=96 agg (fp32, hi/lo bf16 split) + 16 puzzle
#pragma unroll
  for (int ks = 0; ks < 3; ++ks) {
    const float* p = agg + (size_t)row * 96 + ks * 32 + lg * 8;
    short8 ahi, alo;
#pragma unroll
    for (int j = 0; j < 8; ++j) {
      float v = p[j];
      short hiq = f2bf(v);
      ahi[j] = hiq;
      alo[j] = f2bf(v - bf2f(hiq));
    }
#pragma unroll
    for (int nt = 0; nt < 6; ++nt) {
      short8 b = p1g[(ks * 6 + nt) * 64 + l];
      acc[nt] = __builtin_amdgcn_mfma_f32_16x16x32_bf16(ahi, b, acc[nt], 0, 0, 0);
      acc[nt] = __builtin_amdgcn_mfma_f32_16x16x32_bf16(alo, b, acc[nt], 0, 0, 0);
    }
  }
  {
    short8 a;
    if (lg < 2) a = ldrow8(puzzle, (size_t)row * 16 + lg * 8, f32);
    else        a = szero();
#pragma unroll
    for (int nt = 0; nt < 6; ++nt) {
      short8 b = p1g[(3 * 6 + nt) * 64 + l];
      acc[nt] = __builtin_amdgcn_mfma_f32_16x16x32_bf16(a, b, acc[nt], 0, 0, 0);
    }
  }
#pragma unroll
  for (int nt = 0; nt < 6; ++nt) {
    float bb = ldf(pb1, nt * 16 + lr, f32);
#pragma unroll
    for (int r = 0; r < 4; ++r) {
      float v = fmaxf(acc[nt][r] + bb, 0.f);
      act[wv][lg * 4 + r][nt * 16 + lr] = f2bf(v);
    }
    acc[nt] = fzero();
  }
  WAVESYNC();

  // post L2
#pragma unroll
  for (int ks = 0; ks < 3; ++ks) {
    short8 a = *(const short8*)&act[wv][lr][ks * 32 + lg * 8];
#pragma unroll
    for (int nt = 0; nt < 6; ++nt) {
      short8 b = *(const short8*)&p2f[((ks * 6 + nt) * 64 + l) * 8];
      acc[nt] = __builtin_amdgcn_mfma_f32_16x16x32_bf16(a, b, acc[nt], 0, 0, 0);
    }
  }
  WAVESYNC();
#pragma unroll
  for (int nt = 0; nt < 6; ++nt) {
    float bb = ldf(pb2, nt * 16 + lr, f32);
#pragma unroll
    for (int r = 0; r < 4; ++r) {
      float v = fmaxf(acc[nt][r] + bb, 0.f);
      act[wv][lg * 4 + r][nt * 16 + lr] = f2bf(v);
    }
    acc[nt] = fzero();
  }
  WAVESYNC();

  // post L3 (no relu) -> x
#pragma unroll
  for (int ks = 0; ks < 3; ++ks) {
    short8 a = *(const short8*)&act[wv][lr][ks * 32 + lg * 8];
#pragma unroll
    for (int nt = 0; nt < 6; ++nt) {
      short8 b = *(const short8*)&p3f[((ks * 6 + nt) * 64 + l) * 8];
      acc[nt] = __builtin_amdgcn_mfma_f32_16x16x32_bf16(a, b, acc[nt], 0, 0, 0);
    }
  }
  WAVESYNC();
#pragma unroll
  for (int nt = 0; nt < 6; ++nt) {
    float bb = ldf(pb3, nt * 16 + lr, f32);
#pragma unroll
    for (int r = 0; r < 4; ++r) {
      act[wv][lg * 4 + r][nt * 16 + lr] = f2bf(acc[nt][r] + bb);
    }
  }
  WAVESYNC();

  // gates = x@W_ih + h@W_hh
  f32x4 g[24];
#pragma unroll
  for (int nt = 0; nt < 24; ++nt) g[nt] = fzero();
#pragma unroll
  for (int ks = 0; ks < 3; ++ks) {
    short8 ax = *(const short8*)&act[wv][lr][ks * 32 + lg * 8];
    short8 ah = ldrow8(h, (size_t)row * 96 + ks * 32 + lg * 8, f32);
#pragma unroll
    for (int nt = 0; nt < 24; ++nt) {
      short8 bi = ihg[(ks * 24 + nt) * 64 + l];
      g[nt] = __builtin_amdgcn_mfma_f32_16x16x32_bf16(ax, bi, g[nt], 0, 0, 0);
      short8 bh = hhg[(ks * 24 + nt) * 64 + l];
      g[nt] = __builtin_amdgcn_mfma_f32_16x16x32_bf16(ah, bh, g[nt], 0, 0, 0);
    }
  }

  // LSTM elementwise + fp32 writeback; h_new stashed (bf16) into act for the head
#pragma unroll
  for (int nt = 0; nt < 6; ++nt) {
    int col = nt * 16 + lr;
    float bi_i = ldf(bih, col, f32)       + ldf(bhh, col, f32);
    float bi_f = ldf(bih, 96 + col, f32)  + ldf(bhh, 96 + col, f32);
    float bi_g = ldf(bih, 192 + col, f32) + ldf(bhh, 192 + col, f32);
    float bi_o = ldf(bih, 288 + col, f32) + ldf(bhh, 288 + col, f32);
#pragma unroll
    for (int r = 0; r < 4; ++r) {
      int node = n0 + lg * 4 + r;
      float iv = g[nt][r]      + bi_i;
      float fv = g[nt + 6][r]  + bi_f;
      float gv = g[nt + 12][r] + bi_g;
      float ov = g[nt + 18][r] + bi_o;
      float cv = ldf(c, (size_t)node * 96 + col, f32);
      float cn = sigm(fv) * cv + sigm(iv) * tanh_f(gv);
      float hn = sigm(ov) * tanh_f(cn);
      oh0[(size_t)node * 96 + col] = hn;
      oh1[(size_t)node * 96 + col] = hn;
      oc [(size_t)node * 96 + col] = cn;
      act[wv][lg * 4 + r][col] = f2bf(hn);
    }
  }
  WAVESYNC();

  // ---- wave-private head: 16 nodes x 10 outs per wave ----
  for (int idx = l; idx < 160; idx += 64) {
    int nl = idx / 10;                 // 0..15 (node within wave)
    int o = idx - nl * 10;
    const short* hrow = &act[wv][nl][0];
    float a2 = ldf(ob, o, f32);
    for (int k = 0; k < 96; ++k)
      a2 = fmaf(bf2f(hrow[k]), ldf(oW, (size_t)k * 10 + o, f32), a2);
    oo[(size_t)(n0 + nl) * 10 + o] = a2;
  }
}

extern "C" void kernel_launch(void* const* d_in, const int* in_sizes, int n_in,
                              void* d_out, int out_size, void* d_ws, size_t ws_size,
                              hipStream_t stream)
{
  const void* puzzle = d_in[0];
  const void* nodes  = d_in[1];
  const void* ef     = d_in[2];
  const void* h      = d_in[3];
  const void* c      = d_in[4];
  const int*  edges  = (const int*)d_in[5];
  const void* mW1 = d_in[6];  const void* mb1 = d_in[7];
  const void* mW2 = d_in[8];  const void* mb2 = d_in[9];
  const void* mW3 = d_in[10]; const void* mb3 = d_in[11];
  const void* pW1 = d_in[12]; const void* pb1 = d_in[13];
  const void* pW2 = d_in[14]; const void* pb2 = d_in[15];
  const void* pW3 = d_in[16]; const void* pb3 = d_in[17];
  const void* Wih = d_in[18]; const void* bih = d_in[19];
  const void* Whh = d_in[20]; const void* bhh = d_in[21];
  const void* oW  = d_in[22]; const void* ob  = d_in[23];

  char*  ws  = (char*)d_ws;
  int* flags = (int*)(ws + FLG_OFF);
  float* agg = (float*)(ws + AGG_OFF);
  int* cur = (int*)(ws + CUR_OFF);
  float* out = (float*)d_out;
  float* oh0 = out;
  float* oh1 = out + (size_t)NN * 96;
  float* oc  = out + (size_t)2 * NN * 96;
  float* oo  = out + (size_t)3 * NN * 96;

  sniff_kernel<<<1, 64, 0, stream>>>((const unsigned*)nodes, edges, flags);
  zero_all_kernel<<<3888, 256, 0, stream>>>((float4v*)agg, cur);
  relayout_kernel<<<279, 64, 0, stream>>>(mW1, mW2, mW3, pW1, pW2, pW3, Wih, Whh, ws);

  if (ws_size >= (size_t)WS_NEED) {
    int* bsum = (int*)(ws + BSUM_OFF);
    int2* sdst = (int2*)(ws + SRT_OFF);
    short* efb = (short*)(ws + EFB_OFF);
    const int nb = (NN + 1023) / 1024;   // 41

    nb16hist_kernel<<<NE / 256, 256, 0, stream>>>(nodes, ws, (short8*)(ws + NB16_OFF),
                                                  edges, cur);
    scan_local_kernel<<<nb, 1024, 0, stream>>>(cur, bsum);
    scan_tops_kernel<<<1, 64, 0, stream>>>(bsum, nb);
    scan_add_kernel<<<nb, 1024, 0, stream>>>(cur, bsum);
    scatter_kernel<<<NE / 256, 256, 0, stream>>>(edges, ef, ws, cur, sdst, efb);
    edge_kernel<1><<<512, 256, 0, stream>>>(nodes, ef, edges, mb1, mb2, mb3, ws, agg);
  } else {
    edge_kernel<0><<<512, 256, 0, stream>>>(nodes, ef, edges, mb1, mb2, mb3, ws, agg);
  }

  node_kernel<<<NN / 64, 256, 0, stream>>>(agg, puzzle, h, c, pb1, pb2, pb3, bih, bhh,
                                           oW, ob, ws, oh0, oh1, oc, oo);
}